// Round 1
// baseline (548.177 us; speedup 1.0000x reference)
//
#include <hip/hip_runtime.h>
#include <hip/hip_bf16.h>
#include <cstdint>

#define DM   512
#define HID  256
#define NB   128
#define NT   2048
#define NTOK (NB*NT)          // 262144
#define YSZ  (NTOK*6)         // 1572864

typedef __attribute__((ext_vector_type(8)))  _Float16 half8;
typedef __attribute__((ext_vector_type(16))) float    f32x16;

// ---------------- workspace layout (bytes) ----------------
// hs  : f32 [4][128][256]             @ 0        (524288 B)
// WhF : f16 [3][8][16][64][8]         @ 524288   (393216 B)
// WlF : f16 [3][8][16][64][8]         @ 917504   (393216 B)
// AoH : f16 [16][64][8]               @ 1310720  (16384 B)
// AoL : f16 [16][64][8]               @ 1327104  (16384 B)
// total 1343488 B

__device__ __forceinline__ f32x16 zero16() {
    f32x16 v;
#pragma unroll
    for (int e = 0; e < 16; ++e) v[e] = 0.0f;
    return v;
}

// -------- prep: split weights into f16 hi/lo, pre-swizzled into MFMA A-fragment order --------
// A-frag (32x32x16_f16): lane holds A[m = lane&31][k = kstep*16 + (lane>>5)*8 + j], j=0..7
__global__ __launch_bounds__(256) void k_prep_w(const float* __restrict__ As_w,
                                                const float* __restrict__ Ao_w,
                                                _Float16* __restrict__ WhF,
                                                _Float16* __restrict__ WlF,
                                                _Float16* __restrict__ AoH,
                                                _Float16* __restrict__ AoL) {
    int tid = blockIdx.x * 256 + threadIdx.x;
    if (tid < 24576) {                         // 3 layers * 8 mtiles * 16 ksteps * 64 lanes
        int lane  = tid & 63;
        int kstep = (tid >> 6) & 15;
        int mtile = (tid >> 10) & 7;
        int layer = tid >> 13;
        int m  = mtile * 32 + (lane & 31);
        int k0 = kstep * 16 + (lane >> 5) * 8;
        const float* src = As_w + ((size_t)(layer * HID + m)) * HID + k0;
        half8 h, l;
#pragma unroll
        for (int j = 0; j < 8; ++j) {
            float w = src[j];
            _Float16 hh = (_Float16)w;
            h[j] = hh;
            l[j] = (_Float16)((w - (float)hh) * 2048.0f);
        }
        *(half8*)(WhF + (size_t)tid * 8) = h;
        *(half8*)(WlF + (size_t)tid * 8) = l;
    } else if (tid < 25600) {                  // A_out padded to 32 rows: 16 ksteps * 64 lanes
        int q    = tid - 24576;
        int lane = q & 63;
        int row  = lane & 31;
        int k0   = (q >> 6) * 16 + (lane >> 5) * 8;
        half8 h, l;
#pragma unroll
        for (int j = 0; j < 8; ++j) {
            float w = (row < 6) ? Ao_w[row * HID + k0 + j] : 0.0f;
            _Float16 hh = (_Float16)w;
            h[j] = hh;
            l[j] = (_Float16)((w - (float)hh) * 2048.0f);
        }
        *(half8*)(AoH + (size_t)q * 8) = h;
        *(half8*)(AoL + (size_t)q * 8) = l;
    }
}

// -------- prep: modulation MLP (fp32 VALU) + f head. One block per batch row b. --------
__global__ __launch_bounds__(256) void k_mod(const float* __restrict__ Pj,
                                             const float* __restrict__ w0_w, const float* __restrict__ w0_b,
                                             const float* __restrict__ ws_w, const float* __restrict__ ws_b,
                                             const float* __restrict__ c1_w, const float* __restrict__ c1_b,
                                             const float* __restrict__ c2_w, const float* __restrict__ c2_b,
                                             float* __restrict__ hs, float* __restrict__ f_out) {
    __shared__ float pj[DM];
    __shared__ float hcur[HID];
    __shared__ float hf[DM];
    __shared__ float red[HID];
    const int b = blockIdx.x, t = threadIdx.x;
    pj[t]       = Pj[(size_t)b * DM + t];
    pj[t + HID] = Pj[(size_t)b * DM + t + HID];
    __syncthreads();
    {
        float acc = w0_b[t];
        const float* wr = w0_w + (size_t)t * DM;
        for (int k = 0; k < DM; k += 4) {
            float4 w = *(const float4*)(wr + k);
            acc += w.x * pj[k] + w.y * pj[k + 1] + w.z * pj[k + 2] + w.w * pj[k + 3];
        }
        float h = fmaxf(acc, 0.0f);
        hs[(size_t)b * HID + t] = h;
        hcur[t] = h;
    }
    __syncthreads();
    for (int i = 0; i < 3; ++i) {
        float acc = ws_b[i * HID + t];
        const float* wr = ws_w + (size_t)(i * HID + t) * (HID + DM);
        for (int k = 0; k < HID; k += 4) {
            float4 w = *(const float4*)(wr + k);
            acc += w.x * hcur[k] + w.y * hcur[k + 1] + w.z * hcur[k + 2] + w.w * hcur[k + 3];
        }
        for (int k = 0; k < DM; k += 4) {
            float4 w = *(const float4*)(wr + HID + k);
            acc += w.x * pj[k] + w.y * pj[k + 1] + w.z * pj[k + 2] + w.w * pj[k + 3];
        }
        float h = fmaxf(acc, 0.0f);
        hs[(size_t)(i + 1) * NB * HID + (size_t)b * HID + t] = h;
        __syncthreads();
        hcur[t] = h;
        __syncthreads();
    }
    // f head
#pragma unroll
    for (int r = 0; r < 2; ++r) {
        int row = t + r * HID;
        float acc = c1_b[row];
        const float* wr = c1_w + (size_t)row * DM;
        for (int k = 0; k < DM; k += 4) {
            float4 w = *(const float4*)(wr + k);
            acc += w.x * pj[k] + w.y * pj[k + 1] + w.z * pj[k + 2] + w.w * pj[k + 3];
        }
        hf[row] = fmaxf(acc, 0.0f);
    }
    __syncthreads();
    red[t] = c2_w[t] * hf[t] + c2_w[t + HID] * hf[t + HID];
    __syncthreads();
    for (int sft = HID / 2; sft > 0; sft >>= 1) {
        if (t < sft) red[t] += red[t + sft];
        __syncthreads();
    }
    if (t == 0) f_out[b] = 1.0f / (1.0f + expf(-(red[0] + c2_b[0])));
}

// -------- main: fused 3x(256x256) + out layer, transposed-activation MFMA with f16 hi/lo split --------
// Block: 256 threads (4 waves), 64 tokens (2 token-tiles of 32). Wave = 2 M-tiles x 2 token-tiles.
// LDS act layout (elements): [kstep 16][half 2][tt 2][tok 32][8]  -> b128 per lane, conflict-free.
__global__ __launch_bounds__(256, 2) void k_main(const float* __restrict__ s,
                                                 const float* __restrict__ A0_w, const float* __restrict__ A0_b,
                                                 const float* __restrict__ As_b, const float* __restrict__ Ao_b,
                                                 const float* __restrict__ hs,
                                                 const _Float16* __restrict__ WhF, const _Float16* __restrict__ WlF,
                                                 const _Float16* __restrict__ AoH, const _Float16* __restrict__ AoL,
                                                 float* __restrict__ y) {
    __shared__ __align__(16) _Float16 actH[16384];   // 32 KB
    __shared__ __align__(16) _Float16 actL[16384];   // 32 KB
    const int tid  = threadIdx.x;
    const int lane = tid & 63;
    const int wave = tid >> 6;
    const int tokbase = blockIdx.x * 64;
    const int b = tokbase >> 11;
    const float SC = 2048.0f, ISC = (1.0f / 2048.0f);

    // ---- layer 0 fill: x = hs0 * relu(s*a0 + b0), split to f16 hi/lo, token-fragment order
#pragma unroll
    for (int r = 0; r < 8; ++r) {
        int q = tid + 256 * r;                 // q = ((kstep*2+half)*2+tt)*32 + tok
        int tok = q & 31, tt = (q >> 5) & 1;
        int k0 = (q >> 6) * 8;                 // (kstep*2+half)*8 == kstep*16 + half*8
        float sv = s[tokbase + tt * 32 + tok];
        half8 hh, ll;
#pragma unroll
        for (int j = 0; j < 8; ++j) {
            int k = k0 + j;
            float x = fmaf(sv, A0_w[k], A0_b[k]);
            x = hs[b * HID + k] * fmaxf(x, 0.0f);
            _Float16 xh = (_Float16)x;
            hh[j] = xh;
            ll[j] = (_Float16)((x - (float)xh) * SC);
        }
        *(half8*)&actH[q * 8] = hh;
        *(half8*)&actL[q * 8] = ll;
    }
    __syncthreads();

    // ---- 3 FiLM layers
    for (int layer = 0; layer < 3; ++layer) {
        f32x16 a0_[2][2], aC_[2][2];
#pragma unroll
        for (int mt = 0; mt < 2; ++mt)
#pragma unroll
            for (int tt = 0; tt < 2; ++tt) { a0_[mt][tt] = zero16(); aC_[mt][tt] = zero16(); }

        const size_t wbase = (size_t)layer * 65536;
#pragma unroll 2
        for (int kstep = 0; kstep < 16; ++kstep) {
            int abase = ((kstep * 2 + (lane >> 5)) * 2) * 256 + (lane & 31) * 8;
            half8 bh0 = *(const half8*)&actH[abase];
            half8 bl0 = *(const half8*)&actL[abase];
            half8 bh1 = *(const half8*)&actH[abase + 256];
            half8 bl1 = *(const half8*)&actL[abase + 256];
#pragma unroll
            for (int mt = 0; mt < 2; ++mt) {
                int mtile = wave * 2 + mt;
                size_t wo = wbase + (size_t)((mtile * 16 + kstep) * 64 + lane) * 8;
                half8 ah = *(const half8*)&WhF[wo];
                half8 al = *(const half8*)&WlF[wo];
                a0_[mt][0] = __builtin_amdgcn_mfma_f32_32x32x16_f16(ah, bh0, a0_[mt][0], 0, 0, 0);
                aC_[mt][0] = __builtin_amdgcn_mfma_f32_32x32x16_f16(ah, bl0, aC_[mt][0], 0, 0, 0);
                aC_[mt][0] = __builtin_amdgcn_mfma_f32_32x32x16_f16(al, bh0, aC_[mt][0], 0, 0, 0);
                a0_[mt][1] = __builtin_amdgcn_mfma_f32_32x32x16_f16(ah, bh1, a0_[mt][1], 0, 0, 0);
                aC_[mt][1] = __builtin_amdgcn_mfma_f32_32x32x16_f16(ah, bl1, aC_[mt][1], 0, 0, 0);
                aC_[mt][1] = __builtin_amdgcn_mfma_f32_32x32x16_f16(al, bh1, aC_[mt][1], 0, 0, 0);
            }
        }
        __syncthreads();   // all reads of act done before overwrite
        const float* hsl  = hs + (size_t)(layer + 1) * NB * HID + (size_t)b * HID;
        const float* bias = As_b + layer * HID;
#pragma unroll
        for (int mt = 0; mt < 2; ++mt) {
            int mtile = wave * 2 + mt;
#pragma unroll
            for (int reg = 0; reg < 16; ++reg) {
                int m = mtile * 32 + (reg & 3) + 8 * (reg >> 2) + 4 * (lane >> 5);
                float hv = hsl[m], bv = bias[m];
#pragma unroll
                for (int tt = 0; tt < 2; ++tt) {
                    float x = a0_[mt][tt][reg] + aC_[mt][tt][reg] * ISC + bv;
                    x = hv * fmaxf(x, 0.0f);
                    _Float16 xh = (_Float16)x;
                    _Float16 xl = (_Float16)((x - (float)xh) * SC);
                    int eo = (((m >> 4) * 2 + ((m >> 3) & 1)) * 2 + tt) * 256 + (lane & 31) * 8 + (m & 7);
                    actH[eo] = xh;
                    actL[eo] = xl;
                }
            }
        }
        __syncthreads();
    }

    // ---- output layer (K-split across the 4 waves), partial C tiles reduced via LDS
    f32x16 o0[2], oC[2];
#pragma unroll
    for (int tt = 0; tt < 2; ++tt) { o0[tt] = zero16(); oC[tt] = zero16(); }
#pragma unroll
    for (int ks = 0; ks < 4; ++ks) {
        int kstep = wave * 4 + ks;
        int abase = ((kstep * 2 + (lane >> 5)) * 2) * 256 + (lane & 31) * 8;
        half8 bh0 = *(const half8*)&actH[abase];
        half8 bl0 = *(const half8*)&actL[abase];
        half8 bh1 = *(const half8*)&actH[abase + 256];
        half8 bl1 = *(const half8*)&actL[abase + 256];
        size_t wo = (size_t)(kstep * 64 + lane) * 8;
        half8 ah = *(const half8*)&AoH[wo];
        half8 al = *(const half8*)&AoL[wo];
        o0[0] = __builtin_amdgcn_mfma_f32_32x32x16_f16(ah, bh0, o0[0], 0, 0, 0);
        oC[0] = __builtin_amdgcn_mfma_f32_32x32x16_f16(ah, bl0, oC[0], 0, 0, 0);
        oC[0] = __builtin_amdgcn_mfma_f32_32x32x16_f16(al, bh0, oC[0], 0, 0, 0);
        o0[1] = __builtin_amdgcn_mfma_f32_32x32x16_f16(ah, bh1, o0[1], 0, 0, 0);
        oC[1] = __builtin_amdgcn_mfma_f32_32x32x16_f16(ah, bl1, oC[1], 0, 0, 0);
        oC[1] = __builtin_amdgcn_mfma_f32_32x32x16_f16(al, bh1, oC[1], 0, 0, 0);
    }
    __syncthreads();                       // act reads complete; reuse actH as f32 scratch
    float* part = (float*)actH;            // [4 waves][2 tt][32 m][32 tok] = 32 KB
#pragma unroll
    for (int tt = 0; tt < 2; ++tt)
#pragma unroll
        for (int reg = 0; reg < 16; ++reg) {
            int m = (reg & 3) + 8 * (reg >> 2) + 4 * (lane >> 5);
            part[((wave * 2 + tt) * 32 + m) * 32 + (lane & 31)] = o0[tt][reg] + oC[tt][reg] * ISC;
        }
    __syncthreads();
    for (int it = tid; it < 384; it += 256) {     // 2 tt * 6 o * 32 tok
        int tok = it & 31;
        int o   = (it >> 5) % 6;
        int tt  = (it >> 5) / 6;
        float v = Ao_b[o];
#pragma unroll
        for (int w = 0; w < 4; ++w) v += part[((w * 2 + tt) * 32 + o) * 32 + tok];
        y[(size_t)(tokbase + tt * 32 + tok) * 6 + o] = v;
    }
}

extern "C" void kernel_launch(void* const* d_in, const int* in_sizes, int n_in,
                              void* d_out, int out_size, void* d_ws, size_t ws_size,
                              hipStream_t stream) {
    const float* Pj   = (const float*)d_in[0];
    const float* s    = (const float*)d_in[1];
    const float* A0_w = (const float*)d_in[2];
    const float* A0_b = (const float*)d_in[3];
    const float* As_w = (const float*)d_in[4];
    const float* As_b = (const float*)d_in[5];
    const float* Ao_w = (const float*)d_in[6];
    const float* Ao_b = (const float*)d_in[7];
    const float* w0_w = (const float*)d_in[8];
    const float* w0_b = (const float*)d_in[9];
    const float* ws_w = (const float*)d_in[10];
    const float* ws_b = (const float*)d_in[11];
    const float* c1_w = (const float*)d_in[12];
    const float* c1_b = (const float*)d_in[13];
    const float* c2_w = (const float*)d_in[14];
    const float* c2_b = (const float*)d_in[15];

    char* ws = (char*)d_ws;
    float*    hs  = (float*)(ws + 0);
    _Float16* WhF = (_Float16*)(ws + 524288);
    _Float16* WlF = (_Float16*)(ws + 917504);
    _Float16* AoH = (_Float16*)(ws + 1310720);
    _Float16* AoL = (_Float16*)(ws + 1327104);

    float* yout  = (float*)d_out;
    float* f_out = yout + (size_t)YSZ;

    hipLaunchKernelGGL(k_prep_w, dim3(100), dim3(256), 0, stream, As_w, Ao_w, WhF, WlF, AoH, AoL);
    hipLaunchKernelGGL(k_mod, dim3(NB), dim3(256), 0, stream,
                       Pj, w0_w, w0_b, ws_w, ws_b, c1_w, c1_b, c2_w, c2_b, hs, f_out);
    hipLaunchKernelGGL(k_main, dim3(NTOK / 64), dim3(256), 0, stream,
                       s, A0_w, A0_b, As_b, Ao_b, hs, WhF, WlF, AoH, AoL, yout);
}

// Round 8
// 522.881 us; speedup vs baseline: 1.0484x; 1.0484x over previous
//
#include <hip/hip_runtime.h>
#include <hip/hip_bf16.h>
#include <cstdint>

#define DM   512
#define HID  256
#define NB   128
#define NT   2048
#define NTOK (NB*NT)          // 262144
#define YSZ  (NTOK*6)         // 1572864

typedef __attribute__((ext_vector_type(2)))  _Float16 h16x2;
typedef __attribute__((ext_vector_type(4)))  _Float16 h16x4;
typedef __attribute__((ext_vector_type(8)))  _Float16 h16x8;
typedef __attribute__((ext_vector_type(2)))  __fp16   fp16x2;
typedef __attribute__((ext_vector_type(16))) float    f32x16;

// ---------------- workspace layout (bytes) ----------------
// hs  : f32 [4][128][256]             @ 0        (524288 B)
// WhF : f16 [3][8][16][64][8]         @ 524288   (393216 B)
// WlF : f16 [3][8][16][64][8]         @ 917504   (393216 B)
// AoH : f16 [16][64][8]               @ 1310720  (16384 B)
// AoL : f16 [16][64][8]               @ 1327104  (16384 B)

__device__ __forceinline__ f32x16 zero16() {
    f32x16 v;
#pragma unroll
    for (int e = 0; e < 16; ++e) v[e] = 0.0f;
    return v;
}

// split x into f16 hi + f16 lo*2048 (packed, 2 at a time)
// cvt_pkrtz returns __fp16x2; bit-identical to _Float16x2 -> bit_cast
__device__ __forceinline__ void split2(float x0, float x1, h16x2& h, h16x2& l) {
    fp16x2 ph = __builtin_amdgcn_cvt_pkrtz(x0, x1);
    h = __builtin_bit_cast(h16x2, ph);
    float r0 = (x0 - (float)h[0]) * 2048.0f;
    float r1 = (x1 - (float)h[1]) * 2048.0f;
    fp16x2 pl = __builtin_amdgcn_cvt_pkrtz(r0, r1);
    l = __builtin_bit_cast(h16x2, pl);
}

// -------- fused prep: weight split/swizzle (blocks 0..49) + modulation MLP (blocks 50..177) --------
__global__ __launch_bounds__(512) void k_aux(const float* __restrict__ As_w,
                                             const float* __restrict__ Ao_w,
                                             _Float16* __restrict__ WhF,
                                             _Float16* __restrict__ WlF,
                                             _Float16* __restrict__ AoH,
                                             _Float16* __restrict__ AoL,
                                             const float* __restrict__ Pj,
                                             const float* __restrict__ w0_w, const float* __restrict__ w0_b,
                                             const float* __restrict__ ws_w, const float* __restrict__ ws_b,
                                             const float* __restrict__ c1_w, const float* __restrict__ c1_b,
                                             const float* __restrict__ c2_w, const float* __restrict__ c2_b,
                                             float* __restrict__ hs, float* __restrict__ f_out) {
    if (blockIdx.x < 50) {
        // ---- weight prep: A-frag (32x32x16_f16) order: lane holds A[m=lane&31][kstep*16+(lane>>5)*8+j]
        int gid = blockIdx.x * 512 + threadIdx.x;
        if (gid < 24576) {                         // 3 layers * 8 mtiles * 16 ksteps * 64 lanes
            int lane  = gid & 63;
            int kstep = (gid >> 6) & 15;
            int mtile = (gid >> 10) & 7;
            int layer = gid >> 13;
            int m  = mtile * 32 + (lane & 31);
            int k0 = kstep * 16 + (lane >> 5) * 8;
            const float* src = As_w + ((size_t)(layer * HID + m)) * HID + k0;
            h16x8 h, l;
#pragma unroll
            for (int jp = 0; jp < 4; ++jp) {
                h16x2 hh, ll;
                split2(src[2 * jp], src[2 * jp + 1], hh, ll);
                h[2 * jp] = hh[0]; h[2 * jp + 1] = hh[1];
                l[2 * jp] = ll[0]; l[2 * jp + 1] = ll[1];
            }
            *(h16x8*)(WhF + (size_t)gid * 8) = h;
            *(h16x8*)(WlF + (size_t)gid * 8) = l;
        } else {                                   // A_out padded to 32 rows: 16 ksteps * 64 lanes
            int q    = gid - 24576;
            int lane = q & 63;
            int row  = lane & 31;
            int k0   = (q >> 6) * 16 + (lane >> 5) * 8;
            h16x8 h, l;
#pragma unroll
            for (int jp = 0; jp < 4; ++jp) {
                float w0v = (row < 6) ? Ao_w[row * HID + k0 + 2 * jp]     : 0.0f;
                float w1v = (row < 6) ? Ao_w[row * HID + k0 + 2 * jp + 1] : 0.0f;
                h16x2 hh, ll;
                split2(w0v, w1v, hh, ll);
                h[2 * jp] = hh[0]; h[2 * jp + 1] = hh[1];
                l[2 * jp] = ll[0]; l[2 * jp + 1] = ll[1];
            }
            *(h16x8*)(AoH + (size_t)q * 8) = h;
            *(h16x8*)(AoL + (size_t)q * 8) = l;
        }
        return;
    }
    // ---- modulation MLP + f head, one block per batch row, split-K by 2 (t and t+256 share a row)
    __shared__ float pj[DM];
    __shared__ float hcur[HID];
    __shared__ float sum[512];
    __shared__ float hf[DM];
    const int b = blockIdx.x - 50;
    const int t = threadIdx.x;
    const int r = t & 255, half = t >> 8;
    pj[t] = Pj[(size_t)b * DM + t];
    __syncthreads();
    {   // layer 0: out 256, K=512 split 256/256
        float acc = 0.0f;
        const float* wr = w0_w + (size_t)r * DM + half * 256;
        const float* xv = pj + half * 256;
        for (int k = 0; k < 256; k += 4) {
            float4 w = *(const float4*)(wr + k);
            acc += w.x * xv[k] + w.y * xv[k + 1] + w.z * xv[k + 2] + w.w * xv[k + 3];
        }
        sum[t] = acc;
    }
    __syncthreads();
    if (half == 0) {
        float h = fmaxf(sum[r] + sum[r + 256] + w0_b[r], 0.0f);
        hs[(size_t)b * HID + r] = h;
        hcur[r] = h;
    }
    __syncthreads();
    for (int i = 0; i < 3; ++i) {   // out 256, K=768 split 384/384 over concat([hcur, pj])
        float acc = 0.0f;
        const float* wr = ws_w + (size_t)(i * HID + r) * (HID + DM) + half * 384;
        if (half == 0) {
            for (int k = 0; k < 256; k += 4) {
                float4 w = *(const float4*)(wr + k);
                acc += w.x * hcur[k] + w.y * hcur[k + 1] + w.z * hcur[k + 2] + w.w * hcur[k + 3];
            }
            for (int k = 0; k < 128; k += 4) {
                float4 w = *(const float4*)(wr + 256 + k);
                acc += w.x * pj[k] + w.y * pj[k + 1] + w.z * pj[k + 2] + w.w * pj[k + 3];
            }
        } else {
            for (int k = 0; k < 384; k += 4) {
                float4 w = *(const float4*)(wr + k);
                acc += w.x * pj[128 + k] + w.y * pj[129 + k] + w.z * pj[130 + k] + w.w * pj[131 + k];
            }
        }
        sum[t] = acc;
        __syncthreads();
        if (half == 0) {
            float h = fmaxf(sum[r] + sum[r + 256] + ws_b[i * HID + r], 0.0f);
            hs[(size_t)(i + 1) * NB * HID + (size_t)b * HID + r] = h;
            hcur[r] = h;
        }
        __syncthreads();
    }
    {   // f head: c1 512 rows full-K, then dot with c2
        float acc = 0.0f;
        const float* wr = c1_w + (size_t)t * DM;
        for (int k = 0; k < DM; k += 4) {
            float4 w = *(const float4*)(wr + k);
            acc += w.x * pj[k] + w.y * pj[k + 1] + w.z * pj[k + 2] + w.w * pj[k + 3];
        }
        hf[t] = fmaxf(acc + c1_b[t], 0.0f);
    }
    __syncthreads();
    sum[t] = c2_w[t] * hf[t];
    __syncthreads();
    for (int sft = 256; sft > 0; sft >>= 1) {
        if (t < sft) sum[t] += sum[t + sft];
        __syncthreads();
    }
    if (t == 0) f_out[b] = 1.0f / (1.0f + expf(-(sum[0] + c2_b[0])));
}

// -------- main: fused 3x(256x256) + out layer, transposed-activation MFMA, f16 hi/lo split --------
// Block: 256 threads (4 waves), 64 tokens (2 token-tiles of 32). Wave = 2 M-tiles x 2 token-tiles.
// LDS act layout (elements): [kstep 16][half 2][tt 2][tok 32][8]  -> b128 per lane, conflict-free.
__global__ __launch_bounds__(256, 2) void k_main(const float* __restrict__ s,
                                                 const float* __restrict__ A0_w, const float* __restrict__ A0_b,
                                                 const float* __restrict__ As_b, const float* __restrict__ Ao_b,
                                                 const float* __restrict__ hs,
                                                 const _Float16* __restrict__ WhF, const _Float16* __restrict__ WlF,
                                                 const _Float16* __restrict__ AoH, const _Float16* __restrict__ AoL,
                                                 float* __restrict__ y) {
    __shared__ __align__(16) _Float16 actH[16384];   // 32 KB
    __shared__ __align__(16) _Float16 actL[16384];   // 32 KB
    const int tid  = threadIdx.x;
    const int lane = tid & 63;
    const int wave = tid >> 6;
    const int h5   = lane >> 5;
    const int tokbase = blockIdx.x * 64;
    const int b = tokbase >> 11;
    const float ISC = (1.0f / 2048.0f);

    // ---- layer 0 fill: x = hs0 * relu(s*a0 + b0), split to f16 hi/lo, token-fragment order
#pragma unroll
    for (int r = 0; r < 8; ++r) {
        int q = tid + 256 * r;                 // q = ((kstep*2+half)*2+tt)*32 + tok
        int tok = q & 31, tt = (q >> 5) & 1;
        int k0 = (q >> 6) * 8;
        float sv = s[tokbase + tt * 32 + tok];
        h16x8 hh, ll;
#pragma unroll
        for (int jp = 0; jp < 4; ++jp) {
            int k = k0 + 2 * jp;
            float x0 = fmaf(sv, A0_w[k],     A0_b[k]);
            float x1 = fmaf(sv, A0_w[k + 1], A0_b[k + 1]);
            x0 = hs[b * HID + k]     * fmaxf(x0, 0.0f);
            x1 = hs[b * HID + k + 1] * fmaxf(x1, 0.0f);
            h16x2 h2, l2;
            split2(x0, x1, h2, l2);
            hh[2 * jp] = h2[0]; hh[2 * jp + 1] = h2[1];
            ll[2 * jp] = l2[0]; ll[2 * jp + 1] = l2[1];
        }
        *(h16x8*)&actH[q * 8] = hh;
        *(h16x8*)&actL[q * 8] = ll;
    }
    __syncthreads();

    // ---- 3 FiLM layers
    for (int layer = 0; layer < 3; ++layer) {
        f32x16 a0_[2][2], aC_[2][2];
#pragma unroll
        for (int mt = 0; mt < 2; ++mt)
#pragma unroll
            for (int tt = 0; tt < 2; ++tt) { a0_[mt][tt] = zero16(); aC_[mt][tt] = zero16(); }

        const size_t wbase = (size_t)layer * 65536;
#pragma unroll 2
        for (int kstep = 0; kstep < 16; ++kstep) {
            int abase = ((kstep * 2 + h5) * 2) * 256 + (lane & 31) * 8;
            h16x8 bh0 = *(const h16x8*)&actH[abase];
            h16x8 bl0 = *(const h16x8*)&actL[abase];
            h16x8 bh1 = *(const h16x8*)&actH[abase + 256];
            h16x8 bl1 = *(const h16x8*)&actL[abase + 256];
#pragma unroll
            for (int mt = 0; mt < 2; ++mt) {
                int mtile = wave * 2 + mt;
                size_t wo = wbase + (size_t)((mtile * 16 + kstep) * 64 + lane) * 8;
                h16x8 ah = *(const h16x8*)&WhF[wo];
                h16x8 al = *(const h16x8*)&WlF[wo];
                a0_[mt][0] = __builtin_amdgcn_mfma_f32_32x32x16_f16(ah, bh0, a0_[mt][0], 0, 0, 0);
                aC_[mt][0] = __builtin_amdgcn_mfma_f32_32x32x16_f16(ah, bl0, aC_[mt][0], 0, 0, 0);
                aC_[mt][0] = __builtin_amdgcn_mfma_f32_32x32x16_f16(al, bh0, aC_[mt][0], 0, 0, 0);
                a0_[mt][1] = __builtin_amdgcn_mfma_f32_32x32x16_f16(ah, bh1, a0_[mt][1], 0, 0, 0);
                aC_[mt][1] = __builtin_amdgcn_mfma_f32_32x32x16_f16(ah, bl1, aC_[mt][1], 0, 0, 0);
                aC_[mt][1] = __builtin_amdgcn_mfma_f32_32x32x16_f16(al, bh1, aC_[mt][1], 0, 0, 0);
            }
        }
        __syncthreads();   // all reads of act done before overwrite
        const float* hsl  = hs + (size_t)(layer + 1) * NB * HID + (size_t)b * HID;
        const float* bias = As_b + layer * HID;
        // Epilogue: 4 consecutive regs -> 4 consecutive m -> one h16x4 (b64) store, contiguous
        // per-wave addresses => conflict-free.
#pragma unroll
        for (int mt = 0; mt < 2; ++mt) {
            int mtile = wave * 2 + mt;
#pragma unroll
            for (int g = 0; g < 4; ++g) {
                int m0 = mtile * 32 + 8 * g + 4 * h5;
                float4 hv4 = *(const float4*)&hsl[m0];
                float4 bv4 = *(const float4*)&bias[m0];
                int kstep = m0 >> 4, khalf = (m0 >> 3) & 1;
#pragma unroll
                for (int tt = 0; tt < 2; ++tt) {
                    float x0 = hv4.x * fmaxf(a0_[mt][tt][4 * g]     + aC_[mt][tt][4 * g]     * ISC + bv4.x, 0.0f);
                    float x1 = hv4.y * fmaxf(a0_[mt][tt][4 * g + 1] + aC_[mt][tt][4 * g + 1] * ISC + bv4.y, 0.0f);
                    float x2 = hv4.z * fmaxf(a0_[mt][tt][4 * g + 2] + aC_[mt][tt][4 * g + 2] * ISC + bv4.z, 0.0f);
                    float x3 = hv4.w * fmaxf(a0_[mt][tt][4 * g + 3] + aC_[mt][tt][4 * g + 3] * ISC + bv4.w, 0.0f);
                    h16x2 h01, l01, h23, l23;
                    split2(x0, x1, h01, l01);
                    split2(x2, x3, h23, l23);
                    h16x4 hv; hv[0] = h01[0]; hv[1] = h01[1]; hv[2] = h23[0]; hv[3] = h23[1];
                    h16x4 lv; lv[0] = l01[0]; lv[1] = l01[1]; lv[2] = l23[0]; lv[3] = l23[1];
                    int eo = ((kstep * 2 + khalf) * 2 + tt) * 256 + (lane & 31) * 8 + 4 * h5;
                    *(h16x4*)&actH[eo] = hv;
                    *(h16x4*)&actL[eo] = lv;
                }
            }
        }
        __syncthreads();
    }

    // ---- output layer (K-split across the 4 waves), partial C tiles reduced via LDS
    f32x16 o0[2], oC[2];
#pragma unroll
    for (int tt = 0; tt < 2; ++tt) { o0[tt] = zero16(); oC[tt] = zero16(); }
#pragma unroll
    for (int ks = 0; ks < 4; ++ks) {
        int kstep = wave * 4 + ks;
        int abase = ((kstep * 2 + h5) * 2) * 256 + (lane & 31) * 8;
        h16x8 bh0 = *(const h16x8*)&actH[abase];
        h16x8 bl0 = *(const h16x8*)&actL[abase];
        h16x8 bh1 = *(const h16x8*)&actH[abase + 256];
        h16x8 bl1 = *(const h16x8*)&actL[abase + 256];
        size_t wo = (size_t)(kstep * 64 + lane) * 8;
        h16x8 ah = *(const h16x8*)&AoH[wo];
        h16x8 al = *(const h16x8*)&AoL[wo];
        o0[0] = __builtin_amdgcn_mfma_f32_32x32x16_f16(ah, bh0, o0[0], 0, 0, 0);
        oC[0] = __builtin_amdgcn_mfma_f32_32x32x16_f16(ah, bl0, oC[0], 0, 0, 0);
        oC[0] = __builtin_amdgcn_mfma_f32_32x32x16_f16(al, bh0, oC[0], 0, 0, 0);
        o0[1] = __builtin_amdgcn_mfma_f32_32x32x16_f16(ah, bh1, o0[1], 0, 0, 0);
        oC[1] = __builtin_amdgcn_mfma_f32_32x32x16_f16(ah, bl1, oC[1], 0, 0, 0);
        oC[1] = __builtin_amdgcn_mfma_f32_32x32x16_f16(al, bh1, oC[1], 0, 0, 0);
    }
    __syncthreads();                       // act reads complete; reuse actH as f32 scratch
    // only m<8 is ever needed (6 outputs); regs 0..3 hold m = e + 4*h5 in 0..7
    float* part = (float*)actH;            // [4 waves][2 tt][8 m][32 tok] f32 = 8 KB
#pragma unroll
    for (int tt = 0; tt < 2; ++tt)
#pragma unroll
        for (int e = 0; e < 4; ++e) {
            int m = e + 4 * h5;
            part[((wave * 2 + tt) * 8 + m) * 32 + (lane & 31)] = o0[tt][e] + oC[tt][e] * ISC;
        }
    __syncthreads();
    for (int it = tid; it < 384; it += 256) {     // 2 tt * 6 o * 32 tok
        int tok = it & 31;
        int o   = (it >> 5) % 6;
        int tt  = (it >> 5) / 6;
        float v = Ao_b[o];
#pragma unroll
        for (int w = 0; w < 4; ++w) v += part[((w * 2 + tt) * 8 + o) * 32 + tok];
        y[(size_t)(tokbase + tt * 32 + tok) * 6 + o] = v;
    }
}

extern "C" void kernel_launch(void* const* d_in, const int* in_sizes, int n_in,
                              void* d_out, int out_size, void* d_ws, size_t ws_size,
                              hipStream_t stream) {
    const float* Pj   = (const float*)d_in[0];
    const float* s    = (const float*)d_in[1];
    const float* A0_w = (const float*)d_in[2];
    const float* A0_b = (const float*)d_in[3];
    const float* As_w = (const float*)d_in[4];
    const float* As_b = (const float*)d_in[5];
    const float* Ao_w = (const float*)d_in[6];
    const float* Ao_b = (const float*)d_in[7];
    const float* w0_w = (const float*)d_in[8];
    const float* w0_b = (const float*)d_in[9];
    const float* ws_w = (const float*)d_in[10];
    const float* ws_b = (const float*)d_in[11];
    const float* c1_w = (const float*)d_in[12];
    const float* c1_b = (const float*)d_in[13];
    const float* c2_w = (const float*)d_in[14];
    const float* c2_b = (const float*)d_in[15];

    char* ws = (char*)d_ws;
    float*    hs  = (float*)(ws + 0);
    _Float16* WhF = (_Float16*)(ws + 524288);
    _Float16* WlF = (_Float16*)(ws + 917504);
    _Float16* AoH = (_Float16*)(ws + 1310720);
    _Float16* AoL = (_Float16*)(ws + 1327104);

    float* yout  = (float*)d_out;
    float* f_out = yout + (size_t)YSZ;

    hipLaunchKernelGGL(k_aux, dim3(178), dim3(512), 0, stream,
                       As_w, Ao_w, WhF, WlF, AoH, AoL,
                       Pj, w0_w, w0_b, ws_w, ws_b, c1_w, c1_b, c2_w, c2_b, hs, f_out);
    hipLaunchKernelGGL(k_main, dim3(NTOK / 64), dim3(256), 0, stream,
                       s, A0_w, A0_b, As_b, Ao_b, hs, WhF, WlF, AoH, AoL, yout);
}

// Round 9
// 520.549 us; speedup vs baseline: 1.0531x; 1.0045x over previous
//
#include <hip/hip_runtime.h>
#include <hip/hip_bf16.h>
#include <cstdint>

#define DM   512
#define HID  256
#define NB   128
#define NT   2048
#define NTOK (NB*NT)          // 262144
#define YSZ  (NTOK*6)         // 1572864

typedef __attribute__((ext_vector_type(2)))  _Float16 h16x2;
typedef __attribute__((ext_vector_type(4)))  _Float16 h16x4;
typedef __attribute__((ext_vector_type(8)))  _Float16 h16x8;
typedef __attribute__((ext_vector_type(2)))  __fp16   fp16x2;
typedef __attribute__((ext_vector_type(16))) float    f32x16;

// ---------------- workspace layout (bytes) ----------------
// hs  : f32 [4][128][256]             @ 0        (524288 B)
// WhF : f16 [3][8][16][64][8]         @ 524288   (393216 B)
// WlF : f16 [3][8][16][64][8]         @ 917504   (393216 B)
// AoH : f16 [16][64][8]               @ 1310720  (16384 B)
// AoL : f16 [16][64][8]               @ 1327104  (16384 B)

__device__ __forceinline__ f32x16 zero16() {
    f32x16 v;
#pragma unroll
    for (int e = 0; e < 16; ++e) v[e] = 0.0f;
    return v;
}

// split x into f16 hi + f16 lo*2048 (packed, 2 at a time)
// cvt_pkrtz returns __fp16x2; bit-identical to _Float16x2 -> bit_cast
__device__ __forceinline__ void split2(float x0, float x1, h16x2& h, h16x2& l) {
    fp16x2 ph = __builtin_amdgcn_cvt_pkrtz(x0, x1);
    h = __builtin_bit_cast(h16x2, ph);
    float r0 = (x0 - (float)h[0]) * 2048.0f;
    float r1 = (x1 - (float)h[1]) * 2048.0f;
    fp16x2 pl = __builtin_amdgcn_cvt_pkrtz(r0, r1);
    l = __builtin_bit_cast(h16x2, pl);
}

// -------- fused prep: modulation MLP (blocks 0..127) + weight split/swizzle (blocks 128..177) ----
// Mod-MLP rewritten for coalescing: wave = 8 rows x 8 k-lanes; 8 consecutive lanes read one
// row's contiguous 128B (float4 each) -> coalesced; partial dots reduced via 3 shfl_xor steps.
__global__ __launch_bounds__(512) void k_aux(const float* __restrict__ As_w,
                                             const float* __restrict__ Ao_w,
                                             _Float16* __restrict__ WhF,
                                             _Float16* __restrict__ WlF,
                                             _Float16* __restrict__ AoH,
                                             _Float16* __restrict__ AoL,
                                             const float* __restrict__ Pj,
                                             const float* __restrict__ w0_w, const float* __restrict__ w0_b,
                                             const float* __restrict__ ws_w, const float* __restrict__ ws_b,
                                             const float* __restrict__ c1_w, const float* __restrict__ c1_b,
                                             const float* __restrict__ c2_w, const float* __restrict__ c2_b,
                                             float* __restrict__ hs, float* __restrict__ f_out) {
    if (blockIdx.x >= NB) {
        // ---- weight prep: A-frag (32x32x16_f16) order: lane holds A[m=lane&31][kstep*16+(lane>>5)*8+j]
        int gid = (blockIdx.x - NB) * 512 + threadIdx.x;
        if (gid < 24576) {                         // 3 layers * 8 mtiles * 16 ksteps * 64 lanes
            int lane  = gid & 63;
            int kstep = (gid >> 6) & 15;
            int mtile = (gid >> 10) & 7;
            int layer = gid >> 13;
            int m  = mtile * 32 + (lane & 31);
            int k0 = kstep * 16 + (lane >> 5) * 8;
            const float* src = As_w + ((size_t)(layer * HID + m)) * HID + k0;
            h16x8 h, l;
#pragma unroll
            for (int jp = 0; jp < 4; ++jp) {
                h16x2 hh, ll;
                split2(src[2 * jp], src[2 * jp + 1], hh, ll);
                h[2 * jp] = hh[0]; h[2 * jp + 1] = hh[1];
                l[2 * jp] = ll[0]; l[2 * jp + 1] = ll[1];
            }
            *(h16x8*)(WhF + (size_t)gid * 8) = h;
            *(h16x8*)(WlF + (size_t)gid * 8) = l;
        } else {                                   // A_out padded to 32 rows: 16 ksteps * 64 lanes
            int q    = gid - 24576;
            int lane = q & 63;
            int row  = lane & 31;
            int k0   = (q >> 6) * 16 + (lane >> 5) * 8;
            h16x8 h, l;
#pragma unroll
            for (int jp = 0; jp < 4; ++jp) {
                float w0v = (row < 6) ? Ao_w[row * HID + k0 + 2 * jp]     : 0.0f;
                float w1v = (row < 6) ? Ao_w[row * HID + k0 + 2 * jp + 1] : 0.0f;
                h16x2 hh, ll;
                split2(w0v, w1v, hh, ll);
                h[2 * jp] = hh[0]; h[2 * jp + 1] = hh[1];
                l[2 * jp] = ll[0]; l[2 * jp + 1] = ll[1];
            }
            *(h16x8*)(AoH + (size_t)q * 8) = h;
            *(h16x8*)(AoL + (size_t)q * 8) = l;
        }
        return;
    }
    // ---- modulation MLP + f head: one block per batch row, 512 threads = 8 waves.
    // Each wave: 8 rows x 8 k-lanes. Row r's K-range covered strided: lane kl reads
    // float4 at k = it*32 + kl*4 (8 lanes x 16B = 128B contiguous per row) -> coalesced.
    __shared__ float xcat[HID + DM];   // [0:256)=hcur, [256:768)=pj
    __shared__ float hnew[HID];
    __shared__ float hf[DM];
    __shared__ float red[512];
    const int b = blockIdx.x;
    const int t = threadIdx.x;
    const int wave = t >> 6;
    const int kl   = t & 7;            // k-lane within row group
    const int rsub = (t >> 3) & 7;     // row within wave's group of 8
    xcat[HID + t] = Pj[(size_t)b * DM + t];
    __syncthreads();
    // layer 0: 256 rows, K=512 over pj
#pragma unroll
    for (int pass = 0; pass < 4; ++pass) {
        int r = pass * 64 + wave * 8 + rsub;
        const float* wr = w0_w + (size_t)r * DM + kl * 4;
        float acc = 0.0f;
#pragma unroll
        for (int it = 0; it < 16; ++it) {
            float4 w = *(const float4*)(wr + it * 32);
            const float* xp = &xcat[HID + it * 32 + kl * 4];
            acc += w.x * xp[0] + w.y * xp[1] + w.z * xp[2] + w.w * xp[3];
        }
        acc += __shfl_xor(acc, 1);
        acc += __shfl_xor(acc, 2);
        acc += __shfl_xor(acc, 4);
        if (kl == 0) {
            float h = fmaxf(acc + w0_b[r], 0.0f);
            hs[(size_t)b * HID + r] = h;
            hnew[r] = h;
        }
    }
    __syncthreads();
    if (t < HID) xcat[t] = hnew[t];
    // layers 1..3: 256 rows, K=768 over concat([hcur, pj]) = xcat[0:768]
    for (int i = 0; i < 3; ++i) {
        __syncthreads();
#pragma unroll
        for (int pass = 0; pass < 4; ++pass) {
            int r = pass * 64 + wave * 8 + rsub;
            const float* wr = ws_w + (size_t)(i * HID + r) * (HID + DM) + kl * 4;
            float acc = 0.0f;
#pragma unroll
            for (int it = 0; it < 24; ++it) {
                float4 w = *(const float4*)(wr + it * 32);
                const float* xp = &xcat[it * 32 + kl * 4];
                acc += w.x * xp[0] + w.y * xp[1] + w.z * xp[2] + w.w * xp[3];
            }
            acc += __shfl_xor(acc, 1);
            acc += __shfl_xor(acc, 2);
            acc += __shfl_xor(acc, 4);
            if (kl == 0) {
                float h = fmaxf(acc + ws_b[i * HID + r], 0.0f);
                hs[(size_t)(i + 1) * NB * HID + (size_t)b * HID + r] = h;
                hnew[r] = h;
            }
        }
        __syncthreads();
        if (t < HID) xcat[t] = hnew[t];
    }
    __syncthreads();
    // f head: c1 512 rows, K=512 over pj
#pragma unroll
    for (int pass = 0; pass < 8; ++pass) {
        int r = pass * 64 + wave * 8 + rsub;
        const float* wr = c1_w + (size_t)r * DM + kl * 4;
        float acc = 0.0f;
#pragma unroll
        for (int it = 0; it < 16; ++it) {
            float4 w = *(const float4*)(wr + it * 32);
            const float* xp = &xcat[HID + it * 32 + kl * 4];
            acc += w.x * xp[0] + w.y * xp[1] + w.z * xp[2] + w.w * xp[3];
        }
        acc += __shfl_xor(acc, 1);
        acc += __shfl_xor(acc, 2);
        acc += __shfl_xor(acc, 4);
        if (kl == 0) hf[r] = fmaxf(acc + c1_b[r], 0.0f);
    }
    __syncthreads();
    red[t] = c2_w[t] * hf[t];
    __syncthreads();
    for (int sft = 256; sft > 0; sft >>= 1) {
        if (t < sft) red[t] += red[t + sft];
        __syncthreads();
    }
    if (t == 0) f_out[b] = 1.0f / (1.0f + expf(-(red[0] + c2_b[0])));
}

// -------- main: fused 3x(256x256) + out layer, transposed-activation MFMA, f16 hi/lo split --------
// Block: 256 threads (4 waves), 64 tokens (2 token-tiles of 32). Wave = 2 M-tiles x 2 token-tiles.
// LDS act layout (elements): [kstep 16][half 2][tt 2][tok 32][8]  -> b128 per lane, conflict-free.
__global__ __launch_bounds__(256, 2) void k_main(const float* __restrict__ s,
                                                 const float* __restrict__ A0_w, const float* __restrict__ A0_b,
                                                 const float* __restrict__ As_b, const float* __restrict__ Ao_b,
                                                 const float* __restrict__ hs,
                                                 const _Float16* __restrict__ WhF, const _Float16* __restrict__ WlF,
                                                 const _Float16* __restrict__ AoH, const _Float16* __restrict__ AoL,
                                                 float* __restrict__ y) {
    __shared__ __align__(16) _Float16 actH[16384];   // 32 KB
    __shared__ __align__(16) _Float16 actL[16384];   // 32 KB
    const int tid  = threadIdx.x;
    const int lane = tid & 63;
    const int wave = tid >> 6;
    const int h5   = lane >> 5;
    const int tokbase = blockIdx.x * 64;
    const int b = tokbase >> 11;
    const float ISC = (1.0f / 2048.0f);

    // ---- layer 0 fill: x = hs0 * relu(s*a0 + b0), split to f16 hi/lo, token-fragment order
#pragma unroll
    for (int r = 0; r < 8; ++r) {
        int q = tid + 256 * r;                 // q = ((kstep*2+half)*2+tt)*32 + tok
        int tok = q & 31, tt = (q >> 5) & 1;
        int k0 = (q >> 6) * 8;
        float sv = s[tokbase + tt * 32 + tok];
        h16x8 hh, ll;
#pragma unroll
        for (int jp = 0; jp < 4; ++jp) {
            int k = k0 + 2 * jp;
            float x0 = fmaf(sv, A0_w[k],     A0_b[k]);
            float x1 = fmaf(sv, A0_w[k + 1], A0_b[k + 1]);
            x0 = hs[b * HID + k]     * fmaxf(x0, 0.0f);
            x1 = hs[b * HID + k + 1] * fmaxf(x1, 0.0f);
            h16x2 h2, l2;
            split2(x0, x1, h2, l2);
            hh[2 * jp] = h2[0]; hh[2 * jp + 1] = h2[1];
            ll[2 * jp] = l2[0]; ll[2 * jp + 1] = l2[1];
        }
        *(h16x8*)&actH[q * 8] = hh;
        *(h16x8*)&actL[q * 8] = ll;
    }
    __syncthreads();

    // ---- 3 FiLM layers
    for (int layer = 0; layer < 3; ++layer) {
        f32x16 a0_[2][2], aC_[2][2];
#pragma unroll
        for (int mt = 0; mt < 2; ++mt)
#pragma unroll
            for (int tt = 0; tt < 2; ++tt) { a0_[mt][tt] = zero16(); aC_[mt][tt] = zero16(); }

        const size_t wbase = (size_t)layer * 65536;
#pragma unroll 2
        for (int kstep = 0; kstep < 16; ++kstep) {
            int abase = ((kstep * 2 + h5) * 2) * 256 + (lane & 31) * 8;
            h16x8 bh0 = *(const h16x8*)&actH[abase];
            h16x8 bl0 = *(const h16x8*)&actL[abase];
            h16x8 bh1 = *(const h16x8*)&actH[abase + 256];
            h16x8 bl1 = *(const h16x8*)&actL[abase + 256];
#pragma unroll
            for (int mt = 0; mt < 2; ++mt) {
                int mtile = wave * 2 + mt;
                size_t wo = wbase + (size_t)((mtile * 16 + kstep) * 64 + lane) * 8;
                h16x8 ah = *(const h16x8*)&WhF[wo];
                h16x8 al = *(const h16x8*)&WlF[wo];
                a0_[mt][0] = __builtin_amdgcn_mfma_f32_32x32x16_f16(ah, bh0, a0_[mt][0], 0, 0, 0);
                aC_[mt][0] = __builtin_amdgcn_mfma_f32_32x32x16_f16(ah, bl0, aC_[mt][0], 0, 0, 0);
                aC_[mt][0] = __builtin_amdgcn_mfma_f32_32x32x16_f16(al, bh0, aC_[mt][0], 0, 0, 0);
                a0_[mt][1] = __builtin_amdgcn_mfma_f32_32x32x16_f16(ah, bh1, a0_[mt][1], 0, 0, 0);
                aC_[mt][1] = __builtin_amdgcn_mfma_f32_32x32x16_f16(ah, bl1, aC_[mt][1], 0, 0, 0);
                aC_[mt][1] = __builtin_amdgcn_mfma_f32_32x32x16_f16(al, bh1, aC_[mt][1], 0, 0, 0);
            }
        }
        __syncthreads();   // all reads of act done before overwrite
        const float* hsl  = hs + (size_t)(layer + 1) * NB * HID + (size_t)b * HID;
        const float* bias = As_b + layer * HID;
        // Epilogue: 4 consecutive regs -> 4 consecutive m -> one h16x4 (b64) store, contiguous
        // per-wave addresses => conflict-free.
#pragma unroll
        for (int mt = 0; mt < 2; ++mt) {
            int mtile = wave * 2 + mt;
#pragma unroll
            for (int g = 0; g < 4; ++g) {
                int m0 = mtile * 32 + 8 * g + 4 * h5;
                float4 hv4 = *(const float4*)&hsl[m0];
                float4 bv4 = *(const float4*)&bias[m0];
                int kstep = m0 >> 4, khalf = (m0 >> 3) & 1;
#pragma unroll
                for (int tt = 0; tt < 2; ++tt) {
                    float x0 = hv4.x * fmaxf(a0_[mt][tt][4 * g]     + aC_[mt][tt][4 * g]     * ISC + bv4.x, 0.0f);
                    float x1 = hv4.y * fmaxf(a0_[mt][tt][4 * g + 1] + aC_[mt][tt][4 * g + 1] * ISC + bv4.y, 0.0f);
                    float x2 = hv4.z * fmaxf(a0_[mt][tt][4 * g + 2] + aC_[mt][tt][4 * g + 2] * ISC + bv4.z, 0.0f);
                    float x3 = hv4.w * fmaxf(a0_[mt][tt][4 * g + 3] + aC_[mt][tt][4 * g + 3] * ISC + bv4.w, 0.0f);
                    h16x2 h01, l01, h23, l23;
                    split2(x0, x1, h01, l01);
                    split2(x2, x3, h23, l23);
                    h16x4 hv; hv[0] = h01[0]; hv[1] = h01[1]; hv[2] = h23[0]; hv[3] = h23[1];
                    h16x4 lv; lv[0] = l01[0]; lv[1] = l01[1]; lv[2] = l23[0]; lv[3] = l23[1];
                    int eo = ((kstep * 2 + khalf) * 2 + tt) * 256 + (lane & 31) * 8 + 4 * h5;
                    *(h16x4*)&actH[eo] = hv;
                    *(h16x4*)&actL[eo] = lv;
                }
            }
        }
        __syncthreads();
    }

    // ---- output layer (K-split across the 4 waves), partial C tiles reduced via LDS
    f32x16 o0[2], oC[2];
#pragma unroll
    for (int tt = 0; tt < 2; ++tt) { o0[tt] = zero16(); oC[tt] = zero16(); }
#pragma unroll
    for (int ks = 0; ks < 4; ++ks) {
        int kstep = wave * 4 + ks;
        int abase = ((kstep * 2 + h5) * 2) * 256 + (lane & 31) * 8;
        h16x8 bh0 = *(const h16x8*)&actH[abase];
        h16x8 bl0 = *(const h16x8*)&actL[abase];
        h16x8 bh1 = *(const h16x8*)&actH[abase + 256];
        h16x8 bl1 = *(const h16x8*)&actL[abase + 256];
        size_t wo = (size_t)(kstep * 64 + lane) * 8;
        h16x8 ah = *(const h16x8*)&AoH[wo];
        h16x8 al = *(const h16x8*)&AoL[wo];
        o0[0] = __builtin_amdgcn_mfma_f32_32x32x16_f16(ah, bh0, o0[0], 0, 0, 0);
        oC[0] = __builtin_amdgcn_mfma_f32_32x32x16_f16(ah, bl0, oC[0], 0, 0, 0);
        oC[0] = __builtin_amdgcn_mfma_f32_32x32x16_f16(al, bh0, oC[0], 0, 0, 0);
        o0[1] = __builtin_amdgcn_mfma_f32_32x32x16_f16(ah, bh1, o0[1], 0, 0, 0);
        oC[1] = __builtin_amdgcn_mfma_f32_32x32x16_f16(ah, bl1, oC[1], 0, 0, 0);
        oC[1] = __builtin_amdgcn_mfma_f32_32x32x16_f16(al, bh1, oC[1], 0, 0, 0);
    }
    __syncthreads();                       // act reads complete; reuse actH as f32 scratch
    // only m<8 is ever needed (6 outputs); regs 0..3 hold m = e + 4*h5 in 0..7
    float* part = (float*)actH;            // [4 waves][2 tt][8 m][32 tok] f32 = 8 KB
#pragma unroll
    for (int tt = 0; tt < 2; ++tt)
#pragma unroll
        for (int e = 0; e < 4; ++e) {
            int m = e + 4 * h5;
            part[((wave * 2 + tt) * 8 + m) * 32 + (lane & 31)] = o0[tt][e] + oC[tt][e] * ISC;
        }
    __syncthreads();
    for (int it = tid; it < 384; it += 256) {     // 2 tt * 6 o * 32 tok
        int tok = it & 31;
        int o   = (it >> 5) % 6;
        int tt  = (it >> 5) / 6;
        float v = Ao_b[o];
#pragma unroll
        for (int w = 0; w < 4; ++w) v += part[((w * 2 + tt) * 8 + o) * 32 + tok];
        y[(size_t)(tokbase + tt * 32 + tok) * 6 + o] = v;
    }
}

extern "C" void kernel_launch(void* const* d_in, const int* in_sizes, int n_in,
                              void* d_out, int out_size, void* d_ws, size_t ws_size,
                              hipStream_t stream) {
    const float* Pj   = (const float*)d_in[0];
    const float* s    = (const float*)d_in[1];
    const float* A0_w = (const float*)d_in[2];
    const float* A0_b = (const float*)d_in[3];
    const float* As_w = (const float*)d_in[4];
    const float* As_b = (const float*)d_in[5];
    const float* Ao_w = (const float*)d_in[6];
    const float* Ao_b = (const float*)d_in[7];
    const float* w0_w = (const float*)d_in[8];
    const float* w0_b = (const float*)d_in[9];
    const float* ws_w = (const float*)d_in[10];
    const float* ws_b = (const float*)d_in[11];
    const float* c1_w = (const float*)d_in[12];
    const float* c1_b = (const float*)d_in[13];
    const float* c2_w = (const float*)d_in[14];
    const float* c2_b = (const float*)d_in[15];

    char* ws = (char*)d_ws;
    float*    hs  = (float*)(ws + 0);
    _Float16* WhF = (_Float16*)(ws + 524288);
    _Float16* WlF = (_Float16*)(ws + 917504);
    _Float16* AoH = (_Float16*)(ws + 1310720);
    _Float16* AoL = (_Float16*)(ws + 1327104);

    float* yout  = (float*)d_out;
    float* f_out = yout + (size_t)YSZ;

    hipLaunchKernelGGL(k_aux, dim3(178), dim3(512), 0, stream,
                       As_w, Ao_w, WhF, WlF, AoH, AoL,
                       Pj, w0_w, w0_b, ws_w, ws_b, c1_w, c1_b, c2_w, c2_b, hs, f_out);
    hipLaunchKernelGGL(k_main, dim3(NTOK / 64), dim3(256), 0, stream,
                       s, A0_w, A0_b, As_b, Ao_b, hs, WhF, WlF, AoH, AoL, yout);
}

// Round 10
// 472.474 us; speedup vs baseline: 1.1602x; 1.1018x over previous
//
#include <hip/hip_runtime.h>
#include <hip/hip_bf16.h>
#include <cstdint>

#define DM   512
#define HID  256
#define NB   128
#define NT   2048
#define NTOK (NB*NT)          // 262144
#define YSZ  (NTOK*6)         // 1572864

typedef __attribute__((ext_vector_type(2)))  _Float16 h16x2;
typedef __attribute__((ext_vector_type(4)))  _Float16 h16x4;
typedef __attribute__((ext_vector_type(8)))  _Float16 h16x8;
typedef __attribute__((ext_vector_type(2)))  __fp16   fp16x2;
typedef __attribute__((ext_vector_type(16))) float    f32x16;

// ---------------- workspace layout (bytes) ----------------
// hs  : f32 [4][128][256]             @ 0        (524288 B)
// WhF : f16 [3][8][16][64][8]         @ 524288   (393216 B)
// WlF : f16 [3][8][16][64][8]         @ 917504   (393216 B)
// AoH : f16 [16][64][8]               @ 1310720  (16384 B)
// AoL : f16 [16][64][8]               @ 1327104  (16384 B)

__device__ __forceinline__ f32x16 zero16() {
    f32x16 v;
#pragma unroll
    for (int e = 0; e < 16; ++e) v[e] = 0.0f;
    return v;
}

// split x into f16 hi + f16 lo*2048 (packed, 2 at a time)
// cvt_pkrtz returns __fp16x2; bit-identical to _Float16x2 -> bit_cast
__device__ __forceinline__ void split2(float x0, float x1, h16x2& h, h16x2& l) {
    fp16x2 ph = __builtin_amdgcn_cvt_pkrtz(x0, x1);
    h = __builtin_bit_cast(h16x2, ph);
    float r0 = (x0 - (float)h[0]) * 2048.0f;
    float r1 = (x1 - (float)h[1]) * 2048.0f;
    fp16x2 pl = __builtin_amdgcn_cvt_pkrtz(r0, r1);
    l = __builtin_bit_cast(h16x2, pl);
}

// -------- fused prep: mod-MLP (blocks 0..31, 4 batch rows each) + weight prep (blocks 32..81) ----
// Mod-MLP batched: each block handles 4 batch rows, so each weight float4 is loaded once from
// L2/L3 and reused x4 from registers. Aggregate weight traffic 480MB -> 120MB.
__global__ __launch_bounds__(512) void k_aux(const float* __restrict__ As_w,
                                             const float* __restrict__ Ao_w,
                                             _Float16* __restrict__ WhF,
                                             _Float16* __restrict__ WlF,
                                             _Float16* __restrict__ AoH,
                                             _Float16* __restrict__ AoL,
                                             const float* __restrict__ Pj,
                                             const float* __restrict__ w0_w, const float* __restrict__ w0_b,
                                             const float* __restrict__ ws_w, const float* __restrict__ ws_b,
                                             const float* __restrict__ c1_w, const float* __restrict__ c1_b,
                                             const float* __restrict__ c2_w, const float* __restrict__ c2_b,
                                             float* __restrict__ hs, float* __restrict__ f_out) {
    if (blockIdx.x >= 32) {
        // ---- weight prep: A-frag (32x32x16_f16) order: lane holds A[m=lane&31][kstep*16+(lane>>5)*8+j]
        int gid = (blockIdx.x - 32) * 512 + threadIdx.x;
        if (gid < 24576) {                         // 3 layers * 8 mtiles * 16 ksteps * 64 lanes
            int lane  = gid & 63;
            int kstep = (gid >> 6) & 15;
            int mtile = (gid >> 10) & 7;
            int layer = gid >> 13;
            int m  = mtile * 32 + (lane & 31);
            int k0 = kstep * 16 + (lane >> 5) * 8;
            const float* src = As_w + ((size_t)(layer * HID + m)) * HID + k0;
            h16x8 h, l;
#pragma unroll
            for (int jp = 0; jp < 4; ++jp) {
                h16x2 hh, ll;
                split2(src[2 * jp], src[2 * jp + 1], hh, ll);
                h[2 * jp] = hh[0]; h[2 * jp + 1] = hh[1];
                l[2 * jp] = ll[0]; l[2 * jp + 1] = ll[1];
            }
            *(h16x8*)(WhF + (size_t)gid * 8) = h;
            *(h16x8*)(WlF + (size_t)gid * 8) = l;
        } else {                                   // A_out padded to 32 rows: 16 ksteps * 64 lanes
            int q    = gid - 24576;
            int lane = q & 63;
            int row  = lane & 31;
            int k0   = (q >> 6) * 16 + (lane >> 5) * 8;
            h16x8 h, l;
#pragma unroll
            for (int jp = 0; jp < 4; ++jp) {
                float w0v = (row < 6) ? Ao_w[row * HID + k0 + 2 * jp]     : 0.0f;
                float w1v = (row < 6) ? Ao_w[row * HID + k0 + 2 * jp + 1] : 0.0f;
                h16x2 hh, ll;
                split2(w0v, w1v, hh, ll);
                h[2 * jp] = hh[0]; h[2 * jp + 1] = hh[1];
                l[2 * jp] = ll[0]; l[2 * jp + 1] = ll[1];
            }
            *(h16x8*)(AoH + (size_t)q * 8) = h;
            *(h16x8*)(AoL + (size_t)q * 8) = l;
        }
        return;
    }
    // ---- modulation MLP + f head: 4 batch rows per block, 512 threads = 8 waves.
    // wave = 8 rows x 8 k-lanes; lane kl reads float4 at k = it*32 + kl*4 (coalesced);
    // 4 batch-row accumulators share each weight float4; shfl_xor reduce over kl.
    __shared__ float xcat[4][HID + DM];   // per row: [0:256)=hcur, [256:768)=pj
    __shared__ float hnew[4][HID];
    __shared__ float hf4[4][DM];
    __shared__ float red[512];
    const int b0 = blockIdx.x * 4;
    const int t = threadIdx.x;
    const int wave = t >> 6;
    const int kl   = t & 7;
    const int rsub = (t >> 3) & 7;
#pragma unroll
    for (int rb = 0; rb < 4; ++rb)
        xcat[rb][HID + t] = Pj[(size_t)(b0 + rb) * DM + t];
    __syncthreads();
    // layer 0: 256 rows, K=512 over pj
#pragma unroll
    for (int pass = 0; pass < 4; ++pass) {
        int r = pass * 64 + wave * 8 + rsub;
        const float* wr = w0_w + (size_t)r * DM + kl * 4;
        float acc[4] = {0.0f, 0.0f, 0.0f, 0.0f};
#pragma unroll
        for (int it = 0; it < 16; ++it) {
            float4 w = *(const float4*)(wr + it * 32);
            int kx = HID + it * 32 + kl * 4;
#pragma unroll
            for (int rb = 0; rb < 4; ++rb)
                acc[rb] += w.x * xcat[rb][kx]     + w.y * xcat[rb][kx + 1]
                         + w.z * xcat[rb][kx + 2] + w.w * xcat[rb][kx + 3];
        }
#pragma unroll
        for (int rb = 0; rb < 4; ++rb) {
            acc[rb] += __shfl_xor(acc[rb], 1);
            acc[rb] += __shfl_xor(acc[rb], 2);
            acc[rb] += __shfl_xor(acc[rb], 4);
        }
        if (kl == 0) {
            float bv = w0_b[r];
#pragma unroll
            for (int rb = 0; rb < 4; ++rb) {
                float h = fmaxf(acc[rb] + bv, 0.0f);
                hs[(size_t)(b0 + rb) * HID + r] = h;
                hnew[rb][r] = h;
            }
        }
    }
    __syncthreads();
    if (t < HID) {
#pragma unroll
        for (int rb = 0; rb < 4; ++rb) xcat[rb][t] = hnew[rb][t];
    }
    // layers 1..3: 256 rows, K=768 over concat([hcur, pj]) = xcat[rb][0:768)
    for (int i = 0; i < 3; ++i) {
        __syncthreads();
#pragma unroll
        for (int pass = 0; pass < 4; ++pass) {
            int r = pass * 64 + wave * 8 + rsub;
            const float* wr = ws_w + (size_t)(i * HID + r) * (HID + DM) + kl * 4;
            float acc[4] = {0.0f, 0.0f, 0.0f, 0.0f};
#pragma unroll
            for (int it = 0; it < 24; ++it) {
                float4 w = *(const float4*)(wr + it * 32);
                int kx = it * 32 + kl * 4;
#pragma unroll
                for (int rb = 0; rb < 4; ++rb)
                    acc[rb] += w.x * xcat[rb][kx]     + w.y * xcat[rb][kx + 1]
                             + w.z * xcat[rb][kx + 2] + w.w * xcat[rb][kx + 3];
            }
#pragma unroll
            for (int rb = 0; rb < 4; ++rb) {
                acc[rb] += __shfl_xor(acc[rb], 1);
                acc[rb] += __shfl_xor(acc[rb], 2);
                acc[rb] += __shfl_xor(acc[rb], 4);
            }
            if (kl == 0) {
                float bv = ws_b[i * HID + r];
#pragma unroll
                for (int rb = 0; rb < 4; ++rb) {
                    float h = fmaxf(acc[rb] + bv, 0.0f);
                    hs[(size_t)(i + 1) * NB * HID + (size_t)(b0 + rb) * HID + r] = h;
                    hnew[rb][r] = h;
                }
            }
        }
        __syncthreads();
        if (t < HID) {
#pragma unroll
            for (int rb = 0; rb < 4; ++rb) xcat[rb][t] = hnew[rb][t];
        }
    }
    __syncthreads();
    // f head: c1 512 rows, K=512 over pj
#pragma unroll
    for (int pass = 0; pass < 8; ++pass) {
        int r = pass * 64 + wave * 8 + rsub;
        const float* wr = c1_w + (size_t)r * DM + kl * 4;
        float acc[4] = {0.0f, 0.0f, 0.0f, 0.0f};
#pragma unroll
        for (int it = 0; it < 16; ++it) {
            float4 w = *(const float4*)(wr + it * 32);
            int kx = HID + it * 32 + kl * 4;
#pragma unroll
            for (int rb = 0; rb < 4; ++rb)
                acc[rb] += w.x * xcat[rb][kx]     + w.y * xcat[rb][kx + 1]
                         + w.z * xcat[rb][kx + 2] + w.w * xcat[rb][kx + 3];
        }
#pragma unroll
        for (int rb = 0; rb < 4; ++rb) {
            acc[rb] += __shfl_xor(acc[rb], 1);
            acc[rb] += __shfl_xor(acc[rb], 2);
            acc[rb] += __shfl_xor(acc[rb], 4);
        }
        if (kl == 0) {
            float bv = c1_b[r];
#pragma unroll
            for (int rb = 0; rb < 4; ++rb) hf4[rb][r] = fmaxf(acc[rb] + bv, 0.0f);
        }
    }
    __syncthreads();
#pragma unroll
    for (int rb = 0; rb < 4; ++rb) {
        red[t] = c2_w[t] * hf4[rb][t];
        __syncthreads();
        for (int sft = 256; sft > 0; sft >>= 1) {
            if (t < sft) red[t] += red[t + sft];
            __syncthreads();
        }
        if (t == 0) f_out[b0 + rb] = 1.0f / (1.0f + expf(-(red[0] + c2_b[0])));
        __syncthreads();
    }
}

// -------- main: fused 3x(256x256) + out layer, transposed-activation MFMA, f16 hi/lo split --------
// Block: 256 threads (4 waves), 64 tokens (2 token-tiles of 32). Wave = 2 M-tiles x 2 token-tiles.
// LDS act layout (elements): [kstep 16][half 2][tt 2][tok 32][8]  -> b128 per lane, conflict-free.
__global__ __launch_bounds__(256, 2) void k_main(const float* __restrict__ s,
                                                 const float* __restrict__ A0_w, const float* __restrict__ A0_b,
                                                 const float* __restrict__ As_b, const float* __restrict__ Ao_b,
                                                 const float* __restrict__ hs,
                                                 const _Float16* __restrict__ WhF, const _Float16* __restrict__ WlF,
                                                 const _Float16* __restrict__ AoH, const _Float16* __restrict__ AoL,
                                                 float* __restrict__ y) {
    __shared__ __align__(16) _Float16 actH[16384];   // 32 KB
    __shared__ __align__(16) _Float16 actL[16384];   // 32 KB
    const int tid  = threadIdx.x;
    const int lane = tid & 63;
    const int wave = tid >> 6;
    const int h5   = lane >> 5;
    const int tokbase = blockIdx.x * 64;
    const int b = tokbase >> 11;
    const float ISC = (1.0f / 2048.0f);

    // ---- layer 0 fill: x = hs0 * relu(s*a0 + b0), split to f16 hi/lo, token-fragment order
#pragma unroll
    for (int r = 0; r < 8; ++r) {
        int q = tid + 256 * r;                 // q = ((kstep*2+half)*2+tt)*32 + tok
        int tok = q & 31, tt = (q >> 5) & 1;
        int k0 = (q >> 6) * 8;
        float sv = s[tokbase + tt * 32 + tok];
        h16x8 hh, ll;
#pragma unroll
        for (int jp = 0; jp < 4; ++jp) {
            int k = k0 + 2 * jp;
            float x0 = fmaf(sv, A0_w[k],     A0_b[k]);
            float x1 = fmaf(sv, A0_w[k + 1], A0_b[k + 1]);
            x0 = hs[b * HID + k]     * fmaxf(x0, 0.0f);
            x1 = hs[b * HID + k + 1] * fmaxf(x1, 0.0f);
            h16x2 h2, l2;
            split2(x0, x1, h2, l2);
            hh[2 * jp] = h2[0]; hh[2 * jp + 1] = h2[1];
            ll[2 * jp] = l2[0]; ll[2 * jp + 1] = l2[1];
        }
        *(h16x8*)&actH[q * 8] = hh;
        *(h16x8*)&actL[q * 8] = ll;
    }
    __syncthreads();

    // ---- 3 FiLM layers
    for (int layer = 0; layer < 3; ++layer) {
        f32x16 a0_[2][2], aC_[2][2];
#pragma unroll
        for (int mt = 0; mt < 2; ++mt)
#pragma unroll
            for (int tt = 0; tt < 2; ++tt) { a0_[mt][tt] = zero16(); aC_[mt][tt] = zero16(); }

        const size_t wbase = (size_t)layer * 65536;
#pragma unroll 2
        for (int kstep = 0; kstep < 16; ++kstep) {
            int abase = ((kstep * 2 + h5) * 2) * 256 + (lane & 31) * 8;
            h16x8 bh0 = *(const h16x8*)&actH[abase];
            h16x8 bl0 = *(const h16x8*)&actL[abase];
            h16x8 bh1 = *(const h16x8*)&actH[abase + 256];
            h16x8 bl1 = *(const h16x8*)&actL[abase + 256];
#pragma unroll
            for (int mt = 0; mt < 2; ++mt) {
                int mtile = wave * 2 + mt;
                size_t wo = wbase + (size_t)((mtile * 16 + kstep) * 64 + lane) * 8;
                h16x8 ah = *(const h16x8*)&WhF[wo];
                h16x8 al = *(const h16x8*)&WlF[wo];
                a0_[mt][0] = __builtin_amdgcn_mfma_f32_32x32x16_f16(ah, bh0, a0_[mt][0], 0, 0, 0);
                aC_[mt][0] = __builtin_amdgcn_mfma_f32_32x32x16_f16(ah, bl0, aC_[mt][0], 0, 0, 0);
                aC_[mt][0] = __builtin_amdgcn_mfma_f32_32x32x16_f16(al, bh0, aC_[mt][0], 0, 0, 0);
                a0_[mt][1] = __builtin_amdgcn_mfma_f32_32x32x16_f16(ah, bh1, a0_[mt][1], 0, 0, 0);
                aC_[mt][1] = __builtin_amdgcn_mfma_f32_32x32x16_f16(ah, bl1, aC_[mt][1], 0, 0, 0);
                aC_[mt][1] = __builtin_amdgcn_mfma_f32_32x32x16_f16(al, bh1, aC_[mt][1], 0, 0, 0);
            }
        }
        __syncthreads();   // all reads of act done before overwrite
        const float* hsl  = hs + (size_t)(layer + 1) * NB * HID + (size_t)b * HID;
        const float* bias = As_b + layer * HID;
        // Epilogue: 4 consecutive regs -> 4 consecutive m -> one h16x4 (b64) store, contiguous
        // per-wave addresses => conflict-free.
#pragma unroll
        for (int mt = 0; mt < 2; ++mt) {
            int mtile = wave * 2 + mt;
#pragma unroll
            for (int g = 0; g < 4; ++g) {
                int m0 = mtile * 32 + 8 * g + 4 * h5;
                float4 hv4 = *(const float4*)&hsl[m0];
                float4 bv4 = *(const float4*)&bias[m0];
                int kstep = m0 >> 4, khalf = (m0 >> 3) & 1;
#pragma unroll
                for (int tt = 0; tt < 2; ++tt) {
                    float x0 = hv4.x * fmaxf(a0_[mt][tt][4 * g]     + aC_[mt][tt][4 * g]     * ISC + bv4.x, 0.0f);
                    float x1 = hv4.y * fmaxf(a0_[mt][tt][4 * g + 1] + aC_[mt][tt][4 * g + 1] * ISC + bv4.y, 0.0f);
                    float x2 = hv4.z * fmaxf(a0_[mt][tt][4 * g + 2] + aC_[mt][tt][4 * g + 2] * ISC + bv4.z, 0.0f);
                    float x3 = hv4.w * fmaxf(a0_[mt][tt][4 * g + 3] + aC_[mt][tt][4 * g + 3] * ISC + bv4.w, 0.0f);
                    h16x2 h01, l01, h23, l23;
                    split2(x0, x1, h01, l01);
                    split2(x2, x3, h23, l23);
                    h16x4 hv; hv[0] = h01[0]; hv[1] = h01[1]; hv[2] = h23[0]; hv[3] = h23[1];
                    h16x4 lv; lv[0] = l01[0]; lv[1] = l01[1]; lv[2] = l23[0]; lv[3] = l23[1];
                    int eo = ((kstep * 2 + khalf) * 2 + tt) * 256 + (lane & 31) * 8 + 4 * h5;
                    *(h16x4*)&actH[eo] = hv;
                    *(h16x4*)&actL[eo] = lv;
                }
            }
        }
        __syncthreads();
    }

    // ---- output layer (K-split across the 4 waves), partial C tiles reduced via LDS
    f32x16 o0[2], oC[2];
#pragma unroll
    for (int tt = 0; tt < 2; ++tt) { o0[tt] = zero16(); oC[tt] = zero16(); }
#pragma unroll
    for (int ks = 0; ks < 4; ++ks) {
        int kstep = wave * 4 + ks;
        int abase = ((kstep * 2 + h5) * 2) * 256 + (lane & 31) * 8;
        h16x8 bh0 = *(const h16x8*)&actH[abase];
        h16x8 bl0 = *(const h16x8*)&actL[abase];
        h16x8 bh1 = *(const h16x8*)&actH[abase + 256];
        h16x8 bl1 = *(const h16x8*)&actL[abase + 256];
        size_t wo = (size_t)(kstep * 64 + lane) * 8;
        h16x8 ah = *(const h16x8*)&AoH[wo];
        h16x8 al = *(const h16x8*)&AoL[wo];
        o0[0] = __builtin_amdgcn_mfma_f32_32x32x16_f16(ah, bh0, o0[0], 0, 0, 0);
        oC[0] = __builtin_amdgcn_mfma_f32_32x32x16_f16(ah, bl0, oC[0], 0, 0, 0);
        oC[0] = __builtin_amdgcn_mfma_f32_32x32x16_f16(al, bh0, oC[0], 0, 0, 0);
        o0[1] = __builtin_amdgcn_mfma_f32_32x32x16_f16(ah, bh1, o0[1], 0, 0, 0);
        oC[1] = __builtin_amdgcn_mfma_f32_32x32x16_f16(ah, bl1, oC[1], 0, 0, 0);
        oC[1] = __builtin_amdgcn_mfma_f32_32x32x16_f16(al, bh1, oC[1], 0, 0, 0);
    }
    __syncthreads();                       // act reads complete; reuse actH as f32 scratch
    // only m<8 is ever needed (6 outputs); regs 0..3 hold m = e + 4*h5 in 0..7
    float* part = (float*)actH;            // [4 waves][2 tt][8 m][32 tok] f32 = 8 KB
#pragma unroll
    for (int tt = 0; tt < 2; ++tt)
#pragma unroll
        for (int e = 0; e < 4; ++e) {
            int m = e + 4 * h5;
            part[((wave * 2 + tt) * 8 + m) * 32 + (lane & 31)] = o0[tt][e] + oC[tt][e] * ISC;
        }
    __syncthreads();
    for (int it = tid; it < 384; it += 256) {     // 2 tt * 6 o * 32 tok
        int tok = it & 31;
        int o   = (it >> 5) % 6;
        int tt  = (it >> 5) / 6;
        float v = Ao_b[o];
#pragma unroll
        for (int w = 0; w < 4; ++w) v += part[((w * 2 + tt) * 8 + o) * 32 + tok];
        y[(size_t)(tokbase + tt * 32 + tok) * 6 + o] = v;
    }
}

extern "C" void kernel_launch(void* const* d_in, const int* in_sizes, int n_in,
                              void* d_out, int out_size, void* d_ws, size_t ws_size,
                              hipStream_t stream) {
    const float* Pj   = (const float*)d_in[0];
    const float* s    = (const float*)d_in[1];
    const float* A0_w = (const float*)d_in[2];
    const float* A0_b = (const float*)d_in[3];
    const float* As_w = (const float*)d_in[4];
    const float* As_b = (const float*)d_in[5];
    const float* Ao_w = (const float*)d_in[6];
    const float* Ao_b = (const float*)d_in[7];
    const float* w0_w = (const float*)d_in[8];
    const float* w0_b = (const float*)d_in[9];
    const float* ws_w = (const float*)d_in[10];
    const float* ws_b = (const float*)d_in[11];
    const float* c1_w = (const float*)d_in[12];
    const float* c1_b = (const float*)d_in[13];
    const float* c2_w = (const float*)d_in[14];
    const float* c2_b = (const float*)d_in[15];

    char* ws = (char*)d_ws;
    float*    hs  = (float*)(ws + 0);
    _Float16* WhF = (_Float16*)(ws + 524288);
    _Float16* WlF = (_Float16*)(ws + 917504);
    _Float16* AoH = (_Float16*)(ws + 1310720);
    _Float16* AoL = (_Float16*)(ws + 1327104);

    float* yout  = (float*)d_out;
    float* f_out = yout + (size_t)YSZ;

    hipLaunchKernelGGL(k_aux, dim3(82), dim3(512), 0, stream,
                       As_w, Ao_w, WhF, WlF, AoH, AoL,
                       Pj, w0_w, w0_b, ws_w, ws_b, c1_w, c1_b, c2_w, c2_b, hs, f_out);
    hipLaunchKernelGGL(k_main, dim3(NTOK / 64), dim3(256), 0, stream,
                       s, A0_w, A0_b, As_b, Ao_b, hs, WhF, WlF, AoH, AoL, yout);
}

// Round 11
// 430.893 us; speedup vs baseline: 1.2722x; 1.0965x over previous
//
#include <hip/hip_runtime.h>
#include <hip/hip_bf16.h>
#include <cstdint>

#define DM   512
#define HID  256
#define NB   128
#define NT   2048
#define NTOK (NB*NT)          // 262144
#define YSZ  (NTOK*6)         // 1572864

typedef __attribute__((ext_vector_type(2)))  _Float16 h16x2;
typedef __attribute__((ext_vector_type(4)))  _Float16 h16x4;
typedef __attribute__((ext_vector_type(8)))  _Float16 h16x8;
typedef __attribute__((ext_vector_type(2)))  __fp16   fp16x2;
typedef __attribute__((ext_vector_type(16))) float    f32x16;

// ---------------- workspace layout (bytes) ----------------
// hs  : f32 [4][128][256]             @ 0        (524288 B)
// WhF : f16 [3][8][16][64][8]         @ 524288   (393216 B)
// WlF : f16 [3][8][16][64][8]         @ 917504   (393216 B)
// AoH : f16 [16][64][8]               @ 1310720  (16384 B)
// AoL : f16 [16][64][8]               @ 1327104  (16384 B)

__device__ __forceinline__ f32x16 zero16() {
    f32x16 v;
#pragma unroll
    for (int e = 0; e < 16; ++e) v[e] = 0.0f;
    return v;
}

// split x into f16 hi + f16 lo*2048 (packed, 2 at a time)
// cvt_pkrtz returns __fp16x2; bit-identical to _Float16x2 -> bit_cast
__device__ __forceinline__ void split2(float x0, float x1, h16x2& h, h16x2& l) {
    fp16x2 ph = __builtin_amdgcn_cvt_pkrtz(x0, x1);
    h = __builtin_bit_cast(h16x2, ph);
    float r0 = (x0 - (float)h[0]) * 2048.0f;
    float r1 = (x1 - (float)h[1]) * 2048.0f;
    fp16x2 pl = __builtin_amdgcn_cvt_pkrtz(r0, r1);
    l = __builtin_bit_cast(h16x2, pl);
}

// -------- fused prep: mod-MLP (blocks 0..31, 4 batch rows, 16 waves) + weight prep (32..56) ----
// Mod blocks: 1024 threads = 16 waves = 4 waves/SIMD for latency hiding on the 3.75MB/block
// weight stream. Wave = 8 rows x 8 k-lanes; 4 batch-row accumulators share each weight float4.
__global__ __launch_bounds__(1024) void k_aux(const float* __restrict__ As_w,
                                              const float* __restrict__ Ao_w,
                                              _Float16* __restrict__ WhF,
                                              _Float16* __restrict__ WlF,
                                              _Float16* __restrict__ AoH,
                                              _Float16* __restrict__ AoL,
                                              const float* __restrict__ Pj,
                                              const float* __restrict__ w0_w, const float* __restrict__ w0_b,
                                              const float* __restrict__ ws_w, const float* __restrict__ ws_b,
                                              const float* __restrict__ c1_w, const float* __restrict__ c1_b,
                                              const float* __restrict__ c2_w, const float* __restrict__ c2_b,
                                              float* __restrict__ hs, float* __restrict__ f_out) {
    if (blockIdx.x >= 32) {
        // ---- weight prep: A-frag (32x32x16_f16) order: lane holds A[m=lane&31][kstep*16+(lane>>5)*8+j]
        int gid = (blockIdx.x - 32) * 1024 + threadIdx.x;   // 25 blocks x 1024 = 25600 exactly
        if (gid < 24576) {                         // 3 layers * 8 mtiles * 16 ksteps * 64 lanes
            int lane  = gid & 63;
            int kstep = (gid >> 6) & 15;
            int mtile = (gid >> 10) & 7;
            int layer = gid >> 13;
            int m  = mtile * 32 + (lane & 31);
            int k0 = kstep * 16 + (lane >> 5) * 8;
            const float* src = As_w + ((size_t)(layer * HID + m)) * HID + k0;
            h16x8 h, l;
#pragma unroll
            for (int jp = 0; jp < 4; ++jp) {
                h16x2 hh, ll;
                split2(src[2 * jp], src[2 * jp + 1], hh, ll);
                h[2 * jp] = hh[0]; h[2 * jp + 1] = hh[1];
                l[2 * jp] = ll[0]; l[2 * jp + 1] = ll[1];
            }
            *(h16x8*)(WhF + (size_t)gid * 8) = h;
            *(h16x8*)(WlF + (size_t)gid * 8) = l;
        } else {                                   // A_out padded to 32 rows: 16 ksteps * 64 lanes
            int q    = gid - 24576;
            int lane = q & 63;
            int row  = lane & 31;
            int k0   = (q >> 6) * 16 + (lane >> 5) * 8;
            h16x8 h, l;
#pragma unroll
            for (int jp = 0; jp < 4; ++jp) {
                float w0v = (row < 6) ? Ao_w[row * HID + k0 + 2 * jp]     : 0.0f;
                float w1v = (row < 6) ? Ao_w[row * HID + k0 + 2 * jp + 1] : 0.0f;
                h16x2 hh, ll;
                split2(w0v, w1v, hh, ll);
                h[2 * jp] = hh[0]; h[2 * jp + 1] = hh[1];
                l[2 * jp] = ll[0]; l[2 * jp + 1] = ll[1];
            }
            *(h16x8*)(AoH + (size_t)q * 8) = h;
            *(h16x8*)(AoL + (size_t)q * 8) = l;
        }
        return;
    }
    // ---- modulation MLP + f head: 4 batch rows per block, 1024 threads = 16 waves.
    __shared__ float xcat[4][HID + DM];   // per row: [0:256)=hcur, [256:768)=pj
    __shared__ float hnew[4][HID];
    __shared__ float hf4[4][DM];
    __shared__ float red[DM];
    const int b0 = blockIdx.x * 4;
    const int t = threadIdx.x;
    const int wave = t >> 6;           // 0..15
    const int kl   = t & 7;
    const int rsub = (t >> 3) & 7;
    if (t < DM) {
#pragma unroll
        for (int rb = 0; rb < 4; ++rb)
            xcat[rb][HID + t] = Pj[(size_t)(b0 + rb) * DM + t];
    }
    __syncthreads();
    // layer 0: 256 rows, K=512 over pj; 128 rows per pass
#pragma unroll
    for (int pass = 0; pass < 2; ++pass) {
        int r = pass * 128 + wave * 8 + rsub;
        const float* wr = w0_w + (size_t)r * DM + kl * 4;
        float acc[4] = {0.0f, 0.0f, 0.0f, 0.0f};
#pragma unroll
        for (int it = 0; it < 16; ++it) {
            float4 w = *(const float4*)(wr + it * 32);
            int kx = HID + it * 32 + kl * 4;
#pragma unroll
            for (int rb = 0; rb < 4; ++rb)
                acc[rb] += w.x * xcat[rb][kx]     + w.y * xcat[rb][kx + 1]
                         + w.z * xcat[rb][kx + 2] + w.w * xcat[rb][kx + 3];
        }
#pragma unroll
        for (int rb = 0; rb < 4; ++rb) {
            acc[rb] += __shfl_xor(acc[rb], 1);
            acc[rb] += __shfl_xor(acc[rb], 2);
            acc[rb] += __shfl_xor(acc[rb], 4);
        }
        if (kl == 0) {
            float bv = w0_b[r];
#pragma unroll
            for (int rb = 0; rb < 4; ++rb) {
                float h = fmaxf(acc[rb] + bv, 0.0f);
                hs[(size_t)(b0 + rb) * HID + r] = h;
                hnew[rb][r] = h;
            }
        }
    }
    __syncthreads();
    if (t < HID) {
#pragma unroll
        for (int rb = 0; rb < 4; ++rb) xcat[rb][t] = hnew[rb][t];
    }
    // layers 1..3: 256 rows, K=768 over concat([hcur, pj])
    for (int i = 0; i < 3; ++i) {
        __syncthreads();
#pragma unroll
        for (int pass = 0; pass < 2; ++pass) {
            int r = pass * 128 + wave * 8 + rsub;
            const float* wr = ws_w + (size_t)(i * HID + r) * (HID + DM) + kl * 4;
            float acc[4] = {0.0f, 0.0f, 0.0f, 0.0f};
#pragma unroll
            for (int it = 0; it < 24; ++it) {
                float4 w = *(const float4*)(wr + it * 32);
                int kx = it * 32 + kl * 4;
#pragma unroll
                for (int rb = 0; rb < 4; ++rb)
                    acc[rb] += w.x * xcat[rb][kx]     + w.y * xcat[rb][kx + 1]
                             + w.z * xcat[rb][kx + 2] + w.w * xcat[rb][kx + 3];
            }
#pragma unroll
            for (int rb = 0; rb < 4; ++rb) {
                acc[rb] += __shfl_xor(acc[rb], 1);
                acc[rb] += __shfl_xor(acc[rb], 2);
                acc[rb] += __shfl_xor(acc[rb], 4);
            }
            if (kl == 0) {
                float bv = ws_b[i * HID + r];
#pragma unroll
                for (int rb = 0; rb < 4; ++rb) {
                    float h = fmaxf(acc[rb] + bv, 0.0f);
                    hs[(size_t)(i + 1) * NB * HID + (size_t)(b0 + rb) * HID + r] = h;
                    hnew[rb][r] = h;
                }
            }
        }
        __syncthreads();
        if (t < HID) {
#pragma unroll
            for (int rb = 0; rb < 4; ++rb) xcat[rb][t] = hnew[rb][t];
        }
    }
    __syncthreads();
    // f head: c1 512 rows, K=512 over pj; 128 rows per pass
#pragma unroll
    for (int pass = 0; pass < 4; ++pass) {
        int r = pass * 128 + wave * 8 + rsub;
        const float* wr = c1_w + (size_t)r * DM + kl * 4;
        float acc[4] = {0.0f, 0.0f, 0.0f, 0.0f};
#pragma unroll
        for (int it = 0; it < 16; ++it) {
            float4 w = *(const float4*)(wr + it * 32);
            int kx = HID + it * 32 + kl * 4;
#pragma unroll
            for (int rb = 0; rb < 4; ++rb)
                acc[rb] += w.x * xcat[rb][kx]     + w.y * xcat[rb][kx + 1]
                         + w.z * xcat[rb][kx + 2] + w.w * xcat[rb][kx + 3];
        }
#pragma unroll
        for (int rb = 0; rb < 4; ++rb) {
            acc[rb] += __shfl_xor(acc[rb], 1);
            acc[rb] += __shfl_xor(acc[rb], 2);
            acc[rb] += __shfl_xor(acc[rb], 4);
        }
        if (kl == 0) {
            float bv = c1_b[r];
#pragma unroll
            for (int rb = 0; rb < 4; ++rb) hf4[rb][r] = fmaxf(acc[rb] + bv, 0.0f);
        }
    }
    __syncthreads();
#pragma unroll
    for (int rb = 0; rb < 4; ++rb) {
        if (t < DM) red[t] = c2_w[t] * hf4[rb][t];
        __syncthreads();
        for (int sft = 256; sft > 0; sft >>= 1) {
            if (t < sft) red[t] += red[t + sft];
            __syncthreads();
        }
        if (t == 0) f_out[b0 + rb] = 1.0f / (1.0f + expf(-(red[0] + c2_b[0])));
        __syncthreads();
    }
}

// -------- main: fused 3x(256x256) + out layer, transposed-activation MFMA, f16 hi/lo split --------
// Block: 512 threads (8 waves), 64 tokens (2 token-tiles of 32). Wave = 1 M-tile x 2 token-tiles
// (acc 64 VGPR) -> 2 blocks/CU x 8 waves = 4 waves/SIMD.
// LDS act layout (elements): [kstep 16][half 2][tt 2][tok 32][8]  -> b128 per lane.
__global__ __launch_bounds__(512, 4) void k_main(const float* __restrict__ s,
                                                 const float* __restrict__ A0_w, const float* __restrict__ A0_b,
                                                 const float* __restrict__ As_b, const float* __restrict__ Ao_b,
                                                 const float* __restrict__ hs,
                                                 const _Float16* __restrict__ WhF, const _Float16* __restrict__ WlF,
                                                 const _Float16* __restrict__ AoH, const _Float16* __restrict__ AoL,
                                                 float* __restrict__ y) {
    __shared__ __align__(16) _Float16 actH[16384];   // 32 KB
    __shared__ __align__(16) _Float16 actL[16384];   // 32 KB
    const int tid  = threadIdx.x;
    const int lane = tid & 63;
    const int wave = tid >> 6;         // 0..7 = mtile
    const int h5   = lane >> 5;
    const int tokbase = blockIdx.x * 64;
    const int b = tokbase >> 11;
    const float ISC = (1.0f / 2048.0f);

    // ---- layer 0 fill: x = hs0 * relu(s*a0 + b0), split to f16 hi/lo, token-fragment order
#pragma unroll
    for (int r = 0; r < 4; ++r) {
        int q = tid + 512 * r;                 // q = ((kstep*2+half)*2+tt)*32 + tok
        int tok = q & 31, tt = (q >> 5) & 1;
        int k0 = (q >> 6) * 8;
        float sv = s[tokbase + tt * 32 + tok];
        h16x8 hh, ll;
#pragma unroll
        for (int jp = 0; jp < 4; ++jp) {
            int k = k0 + 2 * jp;
            float x0 = fmaf(sv, A0_w[k],     A0_b[k]);
            float x1 = fmaf(sv, A0_w[k + 1], A0_b[k + 1]);
            x0 = hs[b * HID + k]     * fmaxf(x0, 0.0f);
            x1 = hs[b * HID + k + 1] * fmaxf(x1, 0.0f);
            h16x2 h2, l2;
            split2(x0, x1, h2, l2);
            hh[2 * jp] = h2[0]; hh[2 * jp + 1] = h2[1];
            ll[2 * jp] = l2[0]; ll[2 * jp + 1] = l2[1];
        }
        *(h16x8*)&actH[q * 8] = hh;
        *(h16x8*)&actL[q * 8] = ll;
    }
    __syncthreads();

    // ---- 3 FiLM layers
    for (int layer = 0; layer < 3; ++layer) {
        f32x16 a0_[2], aC_[2];                 // [tt]
#pragma unroll
        for (int tt = 0; tt < 2; ++tt) { a0_[tt] = zero16(); aC_[tt] = zero16(); }

        const size_t wbase = (size_t)layer * 65536;
#pragma unroll 2
        for (int kstep = 0; kstep < 16; ++kstep) {
            int abase = ((kstep * 2 + h5) * 2) * 256 + (lane & 31) * 8;
            h16x8 bh0 = *(const h16x8*)&actH[abase];
            h16x8 bl0 = *(const h16x8*)&actL[abase];
            h16x8 bh1 = *(const h16x8*)&actH[abase + 256];
            h16x8 bl1 = *(const h16x8*)&actL[abase + 256];
            size_t wo = wbase + (size_t)((wave * 16 + kstep) * 64 + lane) * 8;
            h16x8 ah = *(const h16x8*)&WhF[wo];
            h16x8 al = *(const h16x8*)&WlF[wo];
            a0_[0] = __builtin_amdgcn_mfma_f32_32x32x16_f16(ah, bh0, a0_[0], 0, 0, 0);
            aC_[0] = __builtin_amdgcn_mfma_f32_32x32x16_f16(ah, bl0, aC_[0], 0, 0, 0);
            aC_[0] = __builtin_amdgcn_mfma_f32_32x32x16_f16(al, bh0, aC_[0], 0, 0, 0);
            a0_[1] = __builtin_amdgcn_mfma_f32_32x32x16_f16(ah, bh1, a0_[1], 0, 0, 0);
            aC_[1] = __builtin_amdgcn_mfma_f32_32x32x16_f16(ah, bl1, aC_[1], 0, 0, 0);
            aC_[1] = __builtin_amdgcn_mfma_f32_32x32x16_f16(al, bh1, aC_[1], 0, 0, 0);
        }
        __syncthreads();   // all reads of act done before overwrite
        const float* hsl  = hs + (size_t)(layer + 1) * NB * HID + (size_t)b * HID;
        const float* bias = As_b + layer * HID;
        // Epilogue: 4 consecutive regs -> 4 consecutive m -> one h16x4 (b64) store.
#pragma unroll
        for (int g = 0; g < 4; ++g) {
            int m0 = wave * 32 + 8 * g + 4 * h5;
            float4 hv4 = *(const float4*)&hsl[m0];
            float4 bv4 = *(const float4*)&bias[m0];
            int kstep = m0 >> 4, khalf = (m0 >> 3) & 1;
#pragma unroll
            for (int tt = 0; tt < 2; ++tt) {
                float x0 = hv4.x * fmaxf(a0_[tt][4 * g]     + aC_[tt][4 * g]     * ISC + bv4.x, 0.0f);
                float x1 = hv4.y * fmaxf(a0_[tt][4 * g + 1] + aC_[tt][4 * g + 1] * ISC + bv4.y, 0.0f);
                float x2 = hv4.z * fmaxf(a0_[tt][4 * g + 2] + aC_[tt][4 * g + 2] * ISC + bv4.z, 0.0f);
                float x3 = hv4.w * fmaxf(a0_[tt][4 * g + 3] + aC_[tt][4 * g + 3] * ISC + bv4.w, 0.0f);
                h16x2 h01, l01, h23, l23;
                split2(x0, x1, h01, l01);
                split2(x2, x3, h23, l23);
                h16x4 hv; hv[0] = h01[0]; hv[1] = h01[1]; hv[2] = h23[0]; hv[3] = h23[1];
                h16x4 lv; lv[0] = l01[0]; lv[1] = l01[1]; lv[2] = l23[0]; lv[3] = l23[1];
                int eo = ((kstep * 2 + khalf) * 2 + tt) * 256 + (lane & 31) * 8 + 4 * h5;
                *(h16x4*)&actH[eo] = hv;
                *(h16x4*)&actL[eo] = lv;
            }
        }
        __syncthreads();
    }

    // ---- output layer (K-split across the 8 waves: 2 ksteps each), reduce via LDS
    f32x16 o0[2], oC[2];
#pragma unroll
    for (int tt = 0; tt < 2; ++tt) { o0[tt] = zero16(); oC[tt] = zero16(); }
#pragma unroll
    for (int ks = 0; ks < 2; ++ks) {
        int kstep = wave * 2 + ks;
        int abase = ((kstep * 2 + h5) * 2) * 256 + (lane & 31) * 8;
        h16x8 bh0 = *(const h16x8*)&actH[abase];
        h16x8 bl0 = *(const h16x8*)&actL[abase];
        h16x8 bh1 = *(const h16x8*)&actH[abase + 256];
        h16x8 bl1 = *(const h16x8*)&actL[abase + 256];
        size_t wo = (size_t)(kstep * 64 + lane) * 8;
        h16x8 ah = *(const h16x8*)&AoH[wo];
        h16x8 al = *(const h16x8*)&AoL[wo];
        o0[0] = __builtin_amdgcn_mfma_f32_32x32x16_f16(ah, bh0, o0[0], 0, 0, 0);
        oC[0] = __builtin_amdgcn_mfma_f32_32x32x16_f16(ah, bl0, oC[0], 0, 0, 0);
        oC[0] = __builtin_amdgcn_mfma_f32_32x32x16_f16(al, bh0, oC[0], 0, 0, 0);
        o0[1] = __builtin_amdgcn_mfma_f32_32x32x16_f16(ah, bh1, o0[1], 0, 0, 0);
        oC[1] = __builtin_amdgcn_mfma_f32_32x32x16_f16(ah, bl1, oC[1], 0, 0, 0);
        oC[1] = __builtin_amdgcn_mfma_f32_32x32x16_f16(al, bh1, oC[1], 0, 0, 0);
    }
    __syncthreads();                       // act reads complete; reuse actH as f32 scratch
    // only m<8 is ever needed (6 outputs); regs 0..3 hold m = e + 4*h5 in 0..7
    float* part = (float*)actH;            // [8 waves][2 tt][8 m][32 tok] f32 = 16 KB
#pragma unroll
    for (int tt = 0; tt < 2; ++tt)
#pragma unroll
        for (int e = 0; e < 4; ++e) {
            int m = e + 4 * h5;
            part[((wave * 2 + tt) * 8 + m) * 32 + (lane & 31)] = o0[tt][e] + oC[tt][e] * ISC;
        }
    __syncthreads();
    for (int it = tid; it < 384; it += 512) {     // 2 tt * 6 o * 32 tok
        int tok = it & 31;
        int o   = (it >> 5) % 6;
        int tt  = (it >> 5) / 6;
        float v = Ao_b[o];
#pragma unroll
        for (int w = 0; w < 8; ++w) v += part[((w * 2 + tt) * 8 + o) * 32 + tok];
        y[(size_t)(tokbase + tt * 32 + tok) * 6 + o] = v;
    }
}

extern "C" void kernel_launch(void* const* d_in, const int* in_sizes, int n_in,
                              void* d_out, int out_size, void* d_ws, size_t ws_size,
                              hipStream_t stream) {
    const float* Pj   = (const float*)d_in[0];
    const float* s    = (const float*)d_in[1];
    const float* A0_w = (const float*)d_in[2];
    const float* A0_b = (const float*)d_in[3];
    const float* As_w = (const float*)d_in[4];
    const float* As_b = (const float*)d_in[5];
    const float* Ao_w = (const float*)d_in[6];
    const float* Ao_b = (const float*)d_in[7];
    const float* w0_w = (const float*)d_in[8];
    const float* w0_b = (const float*)d_in[9];
    const float* ws_w = (const float*)d_in[10];
    const float* ws_b = (const float*)d_in[11];
    const float* c1_w = (const float*)d_in[12];
    const float* c1_b = (const float*)d_in[13];
    const float* c2_w = (const float*)d_in[14];
    const float* c2_b = (const float*)d_in[15];

    char* ws = (char*)d_ws;
    float*    hs  = (float*)(ws + 0);
    _Float16* WhF = (_Float16*)(ws + 524288);
    _Float16* WlF = (_Float16*)(ws + 917504);
    _Float16* AoH = (_Float16*)(ws + 1310720);
    _Float16* AoL = (_Float16*)(ws + 1327104);

    float* yout  = (float*)d_out;
    float* f_out = yout + (size_t)YSZ;

    hipLaunchKernelGGL(k_aux, dim3(57), dim3(1024), 0, stream,
                       As_w, Ao_w, WhF, WlF, AoH, AoL,
                       Pj, w0_w, w0_b, ws_w, ws_b, c1_w, c1_b, c2_w, c2_b, hs, f_out);
    hipLaunchKernelGGL(k_main, dim3(NTOK / 64), dim3(512), 0, stream,
                       s, A0_w, A0_b, As_b, Ao_b, hs, WhF, WlF, AoH, AoL, yout);
}

// Round 14
// 415.068 us; speedup vs baseline: 1.3207x; 1.0381x over previous
//
#include <hip/hip_runtime.h>
#include <hip/hip_bf16.h>
#include <cstdint>

#define DM   512
#define HID  256
#define NB   128
#define NT   2048
#define NTOK (NB*NT)          // 262144
#define YSZ  (NTOK*6)         // 1572864

typedef __attribute__((ext_vector_type(2)))  _Float16 h16x2;
typedef __attribute__((ext_vector_type(4)))  _Float16 h16x4;
typedef __attribute__((ext_vector_type(8)))  _Float16 h16x8;
typedef __attribute__((ext_vector_type(2)))  __fp16   fp16x2;
typedef __attribute__((ext_vector_type(16))) float    f32x16;

// ---------------- workspace layout (bytes) ----------------
// hs  : f32 [4][128][256]             @ 0        (524288 B)
// WhF : f16 [3][8][16][64][8]         @ 524288   (393216 B)
// WlF : f16 [3][8][16][64][8]         @ 917504   (393216 B)
// AoH : f16 [16][64][8]               @ 1310720  (16384 B)
// AoL : f16 [16][64][8]               @ 1327104  (16384 B)

__device__ __forceinline__ f32x16 zero16() {
    f32x16 v;
#pragma unroll
    for (int e = 0; e < 16; ++e) v[e] = 0.0f;
    return v;
}

// split x into f16 hi + f16 lo*2048 (packed, 2 at a time)
// cvt_pkrtz returns __fp16x2; bit-identical to _Float16x2 -> bit_cast
__device__ __forceinline__ void split2(float x0, float x1, h16x2& h, h16x2& l) {
    fp16x2 ph = __builtin_amdgcn_cvt_pkrtz(x0, x1);
    h = __builtin_bit_cast(h16x2, ph);
    float r0 = (x0 - (float)h[0]) * 2048.0f;
    float r1 = (x1 - (float)h[1]) * 2048.0f;
    fp16x2 pl = __builtin_amdgcn_cvt_pkrtz(r0, r1);
    l = __builtin_bit_cast(h16x2, pl);
}

// -------- fused prep: mod-MLP (blocks 0..31, 4 batch rows, 16 waves) + weight prep (32..56) ----
// Mod blocks: 1024 threads = 16 waves = 4 waves/SIMD for latency hiding on the 3.75MB/block
// weight stream. Wave = 8 rows x 8 k-lanes; 4 batch-row accumulators share each weight float4.
__global__ __launch_bounds__(1024) void k_aux(const float* __restrict__ As_w,
                                              const float* __restrict__ Ao_w,
                                              _Float16* __restrict__ WhF,
                                              _Float16* __restrict__ WlF,
                                              _Float16* __restrict__ AoH,
                                              _Float16* __restrict__ AoL,
                                              const float* __restrict__ Pj,
                                              const float* __restrict__ w0_w, const float* __restrict__ w0_b,
                                              const float* __restrict__ ws_w, const float* __restrict__ ws_b,
                                              const float* __restrict__ c1_w, const float* __restrict__ c1_b,
                                              const float* __restrict__ c2_w, const float* __restrict__ c2_b,
                                              float* __restrict__ hs, float* __restrict__ f_out) {
    if (blockIdx.x >= 32) {
        // ---- weight prep: A-frag (32x32x16_f16) order: lane holds A[m=lane&31][kstep*16+(lane>>5)*8+j]
        int gid = (blockIdx.x - 32) * 1024 + threadIdx.x;   // 25 blocks x 1024 = 25600 exactly
        if (gid < 24576) {                         // 3 layers * 8 mtiles * 16 ksteps * 64 lanes
            int lane  = gid & 63;
            int kstep = (gid >> 6) & 15;
            int mtile = (gid >> 10) & 7;
            int layer = gid >> 13;
            int m  = mtile * 32 + (lane & 31);
            int k0 = kstep * 16 + (lane >> 5) * 8;
            const float* src = As_w + ((size_t)(layer * HID + m)) * HID + k0;
            h16x8 h, l;
#pragma unroll
            for (int jp = 0; jp < 4; ++jp) {
                h16x2 hh, ll;
                split2(src[2 * jp], src[2 * jp + 1], hh, ll);
                h[2 * jp] = hh[0]; h[2 * jp + 1] = hh[1];
                l[2 * jp] = ll[0]; l[2 * jp + 1] = ll[1];
            }
            *(h16x8*)(WhF + (size_t)gid * 8) = h;
            *(h16x8*)(WlF + (size_t)gid * 8) = l;
        } else {                                   // A_out padded to 32 rows: 16 ksteps * 64 lanes
            int q    = gid - 24576;
            int lane = q & 63;
            int row  = lane & 31;
            int k0   = (q >> 6) * 16 + (lane >> 5) * 8;
            h16x8 h, l;
#pragma unroll
            for (int jp = 0; jp < 4; ++jp) {
                float w0v = (row < 6) ? Ao_w[row * HID + k0 + 2 * jp]     : 0.0f;
                float w1v = (row < 6) ? Ao_w[row * HID + k0 + 2 * jp + 1] : 0.0f;
                h16x2 hh, ll;
                split2(w0v, w1v, hh, ll);
                h[2 * jp] = hh[0]; h[2 * jp + 1] = hh[1];
                l[2 * jp] = ll[0]; l[2 * jp + 1] = ll[1];
            }
            *(h16x8*)(AoH + (size_t)q * 8) = h;
            *(h16x8*)(AoL + (size_t)q * 8) = l;
        }
        return;
    }
    // ---- modulation MLP + f head: 4 batch rows per block, 1024 threads = 16 waves.
    __shared__ float xcat[4][HID + DM];   // per row: [0:256)=hcur, [256:768)=pj
    __shared__ float hnew[4][HID];
    __shared__ float hf4[4][DM];
    __shared__ float red[DM];
    const int b0 = blockIdx.x * 4;
    const int t = threadIdx.x;
    const int wave = t >> 6;           // 0..15
    const int kl   = t & 7;
    const int rsub = (t >> 3) & 7;
    if (t < DM) {
#pragma unroll
        for (int rb = 0; rb < 4; ++rb)
            xcat[rb][HID + t] = Pj[(size_t)(b0 + rb) * DM + t];
    }
    __syncthreads();
    // layer 0: 256 rows, K=512 over pj; 128 rows per pass
#pragma unroll
    for (int pass = 0; pass < 2; ++pass) {
        int r = pass * 128 + wave * 8 + rsub;
        const float* wr = w0_w + (size_t)r * DM + kl * 4;
        float acc[4] = {0.0f, 0.0f, 0.0f, 0.0f};
#pragma unroll
        for (int it = 0; it < 16; ++it) {
            float4 w = *(const float4*)(wr + it * 32);
            int kx = HID + it * 32 + kl * 4;
#pragma unroll
            for (int rb = 0; rb < 4; ++rb)
                acc[rb] += w.x * xcat[rb][kx]     + w.y * xcat[rb][kx + 1]
                         + w.z * xcat[rb][kx + 2] + w.w * xcat[rb][kx + 3];
        }
#pragma unroll
        for (int rb = 0; rb < 4; ++rb) {
            acc[rb] += __shfl_xor(acc[rb], 1);
            acc[rb] += __shfl_xor(acc[rb], 2);
            acc[rb] += __shfl_xor(acc[rb], 4);
        }
        if (kl == 0) {
            float bv = w0_b[r];
#pragma unroll
            for (int rb = 0; rb < 4; ++rb) {
                float h = fmaxf(acc[rb] + bv, 0.0f);
                hs[(size_t)(b0 + rb) * HID + r] = h;
                hnew[rb][r] = h;
            }
        }
    }
    __syncthreads();
    if (t < HID) {
#pragma unroll
        for (int rb = 0; rb < 4; ++rb) xcat[rb][t] = hnew[rb][t];
    }
    // layers 1..3: 256 rows, K=768 over concat([hcur, pj])
    for (int i = 0; i < 3; ++i) {
        __syncthreads();
#pragma unroll
        for (int pass = 0; pass < 2; ++pass) {
            int r = pass * 128 + wave * 8 + rsub;
            const float* wr = ws_w + (size_t)(i * HID + r) * (HID + DM) + kl * 4;
            float acc[4] = {0.0f, 0.0f, 0.0f, 0.0f};
#pragma unroll
            for (int it = 0; it < 24; ++it) {
                float4 w = *(const float4*)(wr + it * 32);
                int kx = it * 32 + kl * 4;
#pragma unroll
                for (int rb = 0; rb < 4; ++rb)
                    acc[rb] += w.x * xcat[rb][kx]     + w.y * xcat[rb][kx + 1]
                             + w.z * xcat[rb][kx + 2] + w.w * xcat[rb][kx + 3];
            }
#pragma unroll
            for (int rb = 0; rb < 4; ++rb) {
                acc[rb] += __shfl_xor(acc[rb], 1);
                acc[rb] += __shfl_xor(acc[rb], 2);
                acc[rb] += __shfl_xor(acc[rb], 4);
            }
            if (kl == 0) {
                float bv = ws_b[i * HID + r];
#pragma unroll
                for (int rb = 0; rb < 4; ++rb) {
                    float h = fmaxf(acc[rb] + bv, 0.0f);
                    hs[(size_t)(i + 1) * NB * HID + (size_t)(b0 + rb) * HID + r] = h;
                    hnew[rb][r] = h;
                }
            }
        }
        __syncthreads();
        if (t < HID) {
#pragma unroll
            for (int rb = 0; rb < 4; ++rb) xcat[rb][t] = hnew[rb][t];
        }
    }
    __syncthreads();
    // f head: c1 512 rows, K=512 over pj; 128 rows per pass
#pragma unroll
    for (int pass = 0; pass < 4; ++pass) {
        int r = pass * 128 + wave * 8 + rsub;
        const float* wr = c1_w + (size_t)r * DM + kl * 4;
        float acc[4] = {0.0f, 0.0f, 0.0f, 0.0f};
#pragma unroll
        for (int it = 0; it < 16; ++it) {
            float4 w = *(const float4*)(wr + it * 32);
            int kx = HID + it * 32 + kl * 4;
#pragma unroll
            for (int rb = 0; rb < 4; ++rb)
                acc[rb] += w.x * xcat[rb][kx]     + w.y * xcat[rb][kx + 1]
                         + w.z * xcat[rb][kx + 2] + w.w * xcat[rb][kx + 3];
        }
#pragma unroll
        for (int rb = 0; rb < 4; ++rb) {
            acc[rb] += __shfl_xor(acc[rb], 1);
            acc[rb] += __shfl_xor(acc[rb], 2);
            acc[rb] += __shfl_xor(acc[rb], 4);
        }
        if (kl == 0) {
            float bv = c1_b[r];
#pragma unroll
            for (int rb = 0; rb < 4; ++rb) hf4[rb][r] = fmaxf(acc[rb] + bv, 0.0f);
        }
    }
    __syncthreads();
#pragma unroll
    for (int rb = 0; rb < 4; ++rb) {
        if (t < DM) red[t] = c2_w[t] * hf4[rb][t];
        __syncthreads();
        for (int sft = 256; sft > 0; sft >>= 1) {
            if (t < sft) red[t] += red[t + sft];
            __syncthreads();
        }
        if (t == 0) f_out[b0 + rb] = 1.0f / (1.0f + expf(-(red[0] + c2_b[0])));
        __syncthreads();
    }
}

// -------- main: fused 3x(256x256) + out layer, transposed-activation MFMA, f16 hi/lo split --------
// Block: 512 threads (8 waves), 64 tokens (2 token-tiles of 32). Wave = 1 M-tile x 2 token-tiles.
// Compensation uses TWO independent accumulators (aC1 += ah*bl, aC2 += al*bh) so all 6 MFMAs
// per kstep are chain-independent — no dependent-MFMA latency stalls.
// LDS act layout (elements): [kstep 16][half 2][tt 2][tok 32][8]  -> b128 per lane.
__global__ __launch_bounds__(512, 4) void k_main(const float* __restrict__ s,
                                                 const float* __restrict__ A0_w, const float* __restrict__ A0_b,
                                                 const float* __restrict__ As_b, const float* __restrict__ Ao_b,
                                                 const float* __restrict__ hs,
                                                 const _Float16* __restrict__ WhF, const _Float16* __restrict__ WlF,
                                                 const _Float16* __restrict__ AoH, const _Float16* __restrict__ AoL,
                                                 float* __restrict__ y) {
    __shared__ __align__(16) _Float16 actH[16384];   // 32 KB
    __shared__ __align__(16) _Float16 actL[16384];   // 32 KB
    const int tid  = threadIdx.x;
    const int lane = tid & 63;
    const int wave = tid >> 6;         // 0..7 = mtile
    const int h5   = lane >> 5;
    const int tokbase = blockIdx.x * 64;
    const int b = tokbase >> 11;
    const float ISC = (1.0f / 2048.0f);

    // ---- layer 0 fill: x = hs0 * relu(s*a0 + b0), split to f16 hi/lo, token-fragment order
#pragma unroll
    for (int r = 0; r < 4; ++r) {
        int q = tid + 512 * r;                 // q = ((kstep*2+half)*2+tt)*32 + tok
        int tok = q & 31, tt = (q >> 5) & 1;
        int k0 = (q >> 6) * 8;
        float sv = s[tokbase + tt * 32 + tok];
        h16x8 hh, ll;
#pragma unroll
        for (int jp = 0; jp < 4; ++jp) {
            int k = k0 + 2 * jp;
            float x0 = fmaf(sv, A0_w[k],     A0_b[k]);
            float x1 = fmaf(sv, A0_w[k + 1], A0_b[k + 1]);
            x0 = hs[b * HID + k]     * fmaxf(x0, 0.0f);
            x1 = hs[b * HID + k + 1] * fmaxf(x1, 0.0f);
            h16x2 h2, l2;
            split2(x0, x1, h2, l2);
            hh[2 * jp] = h2[0]; hh[2 * jp + 1] = h2[1];
            ll[2 * jp] = l2[0]; ll[2 * jp + 1] = l2[1];
        }
        *(h16x8*)&actH[q * 8] = hh;
        *(h16x8*)&actL[q * 8] = ll;
    }
    __syncthreads();

    // ---- 3 FiLM layers
    for (int layer = 0; layer < 3; ++layer) {
        f32x16 a0_[2], aC1_[2], aC2_[2];       // [tt]
#pragma unroll
        for (int tt = 0; tt < 2; ++tt) { a0_[tt] = zero16(); aC1_[tt] = zero16(); aC2_[tt] = zero16(); }

        const size_t wbase = (size_t)layer * 65536;
#pragma unroll 2
        for (int kstep = 0; kstep < 16; ++kstep) {
            int abase = ((kstep * 2 + h5) * 2) * 256 + (lane & 31) * 8;
            h16x8 bh0 = *(const h16x8*)&actH[abase];
            h16x8 bl0 = *(const h16x8*)&actL[abase];
            h16x8 bh1 = *(const h16x8*)&actH[abase + 256];
            h16x8 bl1 = *(const h16x8*)&actL[abase + 256];
            size_t wo = wbase + (size_t)((wave * 16 + kstep) * 64 + lane) * 8;
            h16x8 ah = *(const h16x8*)&WhF[wo];
            h16x8 al = *(const h16x8*)&WlF[wo];
            a0_[0]  = __builtin_amdgcn_mfma_f32_32x32x16_f16(ah, bh0, a0_[0],  0, 0, 0);
            aC1_[0] = __builtin_amdgcn_mfma_f32_32x32x16_f16(ah, bl0, aC1_[0], 0, 0, 0);
            aC2_[0] = __builtin_amdgcn_mfma_f32_32x32x16_f16(al, bh0, aC2_[0], 0, 0, 0);
            a0_[1]  = __builtin_amdgcn_mfma_f32_32x32x16_f16(ah, bh1, a0_[1],  0, 0, 0);
            aC1_[1] = __builtin_amdgcn_mfma_f32_32x32x16_f16(ah, bl1, aC1_[1], 0, 0, 0);
            aC2_[1] = __builtin_amdgcn_mfma_f32_32x32x16_f16(al, bh1, aC2_[1], 0, 0, 0);
        }
        __syncthreads();   // all reads of act done before overwrite
        const float* hsl  = hs + (size_t)(layer + 1) * NB * HID + (size_t)b * HID;
        const float* bias = As_b + layer * HID;
        // Epilogue: 4 consecutive regs -> 4 consecutive m -> one h16x4 (b64) store.
#pragma unroll
        for (int g = 0; g < 4; ++g) {
            int m0 = wave * 32 + 8 * g + 4 * h5;
            float4 hv4 = *(const float4*)&hsl[m0];
            float4 bv4 = *(const float4*)&bias[m0];
            int kstep = m0 >> 4, khalf = (m0 >> 3) & 1;
#pragma unroll
            for (int tt = 0; tt < 2; ++tt) {
                float x0 = hv4.x * fmaxf(a0_[tt][4 * g]     + (aC1_[tt][4 * g]     + aC2_[tt][4 * g])     * ISC + bv4.x, 0.0f);
                float x1 = hv4.y * fmaxf(a0_[tt][4 * g + 1] + (aC1_[tt][4 * g + 1] + aC2_[tt][4 * g + 1]) * ISC + bv4.y, 0.0f);
                float x2 = hv4.z * fmaxf(a0_[tt][4 * g + 2] + (aC1_[tt][4 * g + 2] + aC2_[tt][4 * g + 2]) * ISC + bv4.z, 0.0f);
                float x3 = hv4.w * fmaxf(a0_[tt][4 * g + 3] + (aC1_[tt][4 * g + 3] + aC2_[tt][4 * g + 3]) * ISC + bv4.w, 0.0f);
                h16x2 h01, l01, h23, l23;
                split2(x0, x1, h01, l01);
                split2(x2, x3, h23, l23);
                h16x4 hv; hv[0] = h01[0]; hv[1] = h01[1]; hv[2] = h23[0]; hv[3] = h23[1];
                h16x4 lv; lv[0] = l01[0]; lv[1] = l01[1]; lv[2] = l23[0]; lv[3] = l23[1];
                int eo = ((kstep * 2 + khalf) * 2 + tt) * 256 + (lane & 31) * 8 + 4 * h5;
                *(h16x4*)&actH[eo] = hv;
                *(h16x4*)&actL[eo] = lv;
            }
        }
        __syncthreads();
    }

    // ---- output layer (K-split across the 8 waves: 2 ksteps each), reduce via LDS
    f32x16 o0[2], oC1[2], oC2[2];
#pragma unroll
    for (int tt = 0; tt < 2; ++tt) { o0[tt] = zero16(); oC1[tt] = zero16(); oC2[tt] = zero16(); }
#pragma unroll
    for (int ks = 0; ks < 2; ++ks) {
        int kstep = wave * 2 + ks;
        int abase = ((kstep * 2 + h5) * 2) * 256 + (lane & 31) * 8;
        h16x8 bh0 = *(const h16x8*)&actH[abase];
        h16x8 bl0 = *(const h16x8*)&actL[abase];
        h16x8 bh1 = *(const h16x8*)&actH[abase + 256];
        h16x8 bl1 = *(const h16x8*)&actL[abase + 256];
        size_t wo = (size_t)(kstep * 64 + lane) * 8;
        h16x8 ah = *(const h16x8*)&AoH[wo];
        h16x8 al = *(const h16x8*)&AoL[wo];
        o0[0]  = __builtin_amdgcn_mfma_f32_32x32x16_f16(ah, bh0, o0[0],  0, 0, 0);
        oC1[0] = __builtin_amdgcn_mfma_f32_32x32x16_f16(ah, bl0, oC1[0], 0, 0, 0);
        oC2[0] = __builtin_amdgcn_mfma_f32_32x32x16_f16(al, bh0, oC2[0], 0, 0, 0);
        o0[1]  = __builtin_amdgcn_mfma_f32_32x32x16_f16(ah, bh1, o0[1],  0, 0, 0);
        oC1[1] = __builtin_amdgcn_mfma_f32_32x32x16_f16(ah, bl1, oC1[1], 0, 0, 0);
        oC2[1] = __builtin_amdgcn_mfma_f32_32x32x16_f16(al, bh1, oC2[1], 0, 0, 0);
    }
    __syncthreads();                       // act reads complete; reuse actH as f32 scratch
    // only m<8 is ever needed (6 outputs); regs 0..3 hold m = e + 4*h5 in 0..7
    float* part = (float*)actH;            // [8 waves][2 tt][8 m][32 tok] f32 = 16 KB
#pragma unroll
    for (int tt = 0; tt < 2; ++tt)
#pragma unroll
        for (int e = 0; e < 4; ++e) {
            int m = e + 4 * h5;
            part[((wave * 2 + tt) * 8 + m) * 32 + (lane & 31)] = o0[tt][e] + (oC1[tt][e] + oC2[tt][e]) * ISC;
        }
    __syncthreads();
    for (int it = tid; it < 384; it += 512) {     // 2 tt * 6 o * 32 tok
        int tok = it & 31;
        int o   = (it >> 5) % 6;
        int tt  = (it >> 5) / 6;
        float v = Ao_b[o];
#pragma unroll
        for (int w = 0; w < 8; ++w) v += part[((w * 2 + tt) * 8 + o) * 32 + tok];
        y[(size_t)(tokbase + tt * 32 + tok) * 6 + o] = v;
    }
}

extern "C" void kernel_launch(void* const* d_in, const int* in_sizes, int n_in,
                              void* d_out, int out_size, void* d_ws, size_t ws_size,
                              hipStream_t stream) {
    const float* Pj   = (const float*)d_in[0];
    const float* s    = (const float*)d_in[1];
    const float* A0_w = (const float*)d_in[2];
    const float* A0_b = (const float*)d_in[3];
    const float* As_w = (const float*)d_in[4];
    const float* As_b = (const float*)d_in[5];
    const float* Ao_w = (const float*)d_in[6];
    const float* Ao_b = (const float*)d_in[7];
    const float* w0_w = (const float*)d_in[8];
    const float* w0_b = (const float*)d_in[9];
    const float* ws_w = (const float*)d_in[10];
    const float* ws_b = (const float*)d_in[11];
    const float* c1_w = (const float*)d_in[12];
    const float* c1_b = (const float*)d_in[13];
    const float* c2_w = (const float*)d_in[14];
    const float* c2_b = (const float*)d_in[15];

    char* ws = (char*)d_ws;
    float*    hs  = (float*)(ws + 0);
    _Float16* WhF = (_Float16*)(ws + 524288);
    _Float16* WlF = (_Float16*)(ws + 917504);
    _Float16* AoH = (_Float16*)(ws + 1310720);
    _Float16* AoL = (_Float16*)(ws + 1327104);

    float* yout  = (float*)d_out;
    float* f_out = yout + (size_t)YSZ;

    hipLaunchKernelGGL(k_aux, dim3(57), dim3(1024), 0, stream,
                       As_w, Ao_w, WhF, WlF, AoH, AoL,
                       Pj, w0_w, w0_b, ws_w, ws_b, c1_w, c1_b, c2_w, c2_b, hs, f_out);
    hipLaunchKernelGGL(k_main, dim3(NTOK / 64), dim3(512), 0, stream,
                       s, A0_w, A0_b, As_b, Ao_b, hs, WhF, WlF, AoH, AoL, yout);
}